// Round 13
// baseline (515.649 us; speedup 1.0000x reference)
//
#include <hip/hip_runtime.h>
#include <cstdint>
#include <cstddef>

#define DD 128
#define LSTMH 256
#define ZG 1024

typedef __attribute__((ext_vector_type(8))) short short8v;
typedef __attribute__((ext_vector_type(4))) float float4v;

static inline int cdiv_(int a, int b) { return (a + b - 1) / b; }

__device__ __forceinline__ float sigm_(float x) { return 1.f / (1.f + __expf(-x)); }
__device__ __forceinline__ float tanh_(float x) {
  float e = __expf(-2.f * fabsf(x));
  float r = (1.f - e) / (1.f + e);
  return copysignf(r, x);
}

__device__ __forceinline__ unsigned short f2bf(float f) {
  uint32_t u = __float_as_uint(f);
  u += 0x7fffu + ((u >> 16) & 1u);
  return (unsigned short)(u >> 16);
}
__device__ __forceinline__ uint32_t bfpack(float a, float b) {
  return (uint32_t)f2bf(a) | ((uint32_t)f2bf(b) << 16);
}
__device__ __forceinline__ float bflo(uint32_t u) { return __uint_as_float(u << 16); }
__device__ __forceinline__ float bfhi(uint32_t u) { return __uint_as_float(u & 0xffff0000u); }

// ------- fused prep: 5 transposes + 2 casts + biases + deg/cursor/pooled zero, 1 launch --
__global__ void prep_all(const float* __restrict__ g1Wl, const float* __restrict__ g1Wr,
                         const float* __restrict__ g2Wl, const float* __restrict__ g2Wr,
                         const float* __restrict__ Wres, const float* __restrict__ l1Wih,
                         const float* __restrict__ l2Wih, const float* __restrict__ g1bl,
                         const float* __restrict__ g1br, const float* __restrict__ g2bl,
                         const float* __restrict__ g2br, const float* __restrict__ bres,
                         const float* __restrict__ l1bih, const float* __restrict__ l1bhh,
                         const float* __restrict__ l2bih, const float* __restrict__ l2bhh,
                         unsigned short* __restrict__ wcat1, unsigned short* __restrict__ wcat2,
                         unsigned short* __restrict__ wl1b, unsigned short* __restrict__ wl2b,
                         float* __restrict__ bcat1, float* __restrict__ bcat2,
                         float* __restrict__ bsum1, float* __restrict__ bsum2,
                         int* __restrict__ deg, int* __restrict__ cursor,
                         float* __restrict__ pooled, int Nn) {
  int i = blockIdx.x * 256 + threadIdx.x;
  if (i < 81920) {  // five 128x128 transposes -> [M][K] bf16
    int seg = i >> 14, j = i & 16383;
    int m = j >> 7, k = j & 127;
    const float* src = (seg == 0) ? g1Wl : (seg == 1) ? g1Wr : (seg == 2) ? g2Wl
                       : (seg == 3) ? g2Wr : Wres;
    unsigned short* dst = (seg == 0) ? wcat1 : (seg == 1) ? wcat1 + 16384
                          : (seg == 2) ? wcat2 : (seg == 3) ? wcat2 + 16384 : wcat2 + 32768;
    dst[j] = f2bf(src[k * 128 + m]);
    return;
  }
  i -= 81920;
  if (i < 131072) { wl1b[i] = f2bf(l1Wih[i]); return; }
  i -= 131072;
  if (i < 262144) { wl2b[i] = f2bf(l2Wih[i]); return; }
  i -= 262144;
  if (i < 256) { bcat1[i] = (i < 128) ? g1bl[i] : g1br[i - 128]; return; }
  i -= 256;
  if (i < 384) {
    bcat2[i] = (i < 128) ? g2bl[i] : (i < 256 ? g2br[i - 128] : bres[i - 256]);
    return;
  }
  i -= 384;
  if (i < 1024) { bsum1[i] = l1bih[i] + l1bhh[i]; return; }
  i -= 1024;
  if (i < 1024) { bsum2[i] = l2bih[i] + l2bhh[i]; return; }
  i -= 1024;
  if (i < Nn) { deg[i] = 0; return; }
  i -= Nn;
  if (i < Nn) { cursor[i] = 0; return; }
  i -= Nn;
  if (i < 16384) { pooled[i] = 0.f; return; }
}

// ---------------- embedding + W_in GEMV: 128 nodes/block, W in registers ----------------
__global__ __launch_bounds__(256) void embed_in2(
    const int* __restrict__ labels, const int* __restrict__ types,
    const float* __restrict__ nf, const float* __restrict__ embL,
    const float* __restrict__ embT, const float* __restrict__ W,
    const float* __restrict__ b, unsigned short* __restrict__ x, int N) {
  __shared__ float f[128][34];
  int base = blockIdx.x * 128;
  int tid = threadIdx.x;
  int ch = tid & 127, half = tid >> 7;
  float wr[33];
#pragma unroll
  for (int k = 0; k < 33; ++k) wr[k] = W[k * 128 + ch];
  float bb = b[ch];
  int nmax = N - base < 128 ? N - base : 128;
  for (int e = tid; e < nmax * 32; e += 256) {
    int n = e >> 5, k = e & 31;
    f[n][k] = (k < 16) ? embL[labels[base + n] * 16 + k] : embT[types[base + n] * 16 + (k - 16)];
  }
  for (int n = tid; n < nmax; n += 256) f[n][32] = nf[base + n];
  __syncthreads();
  for (int n = half; n < nmax; n += 2) {
    float acc = bb;
#pragma unroll
    for (int k = 0; k < 33; ++k) acc = fmaf(f[n][k], wr[k], acc);
    x[(size_t)(base + n) * 128 + ch] = f2bf(acc);
  }
}

// ---------------- CSR build ----------------
__global__ void count_deg(const int* __restrict__ ei, int* __restrict__ deg, int E_, int N_) {
  int i = blockIdx.x * 256 + threadIdx.x;
  if (i < E_) atomicAdd(&deg[ei[E_ + i]], 1);
  else if (i < E_ + N_) atomicAdd(&deg[i - E_], 1);
}

__global__ __launch_bounds__(256) void scan1(const int* __restrict__ deg, int* __restrict__ offs,
                                             int* __restrict__ partials, int N_) {
  __shared__ int buf[2][256];
  int tid = threadIdx.x;
  int i = blockIdx.x * 256 + tid;
  int v = (i < N_) ? deg[i] : 0;
  buf[0][tid] = v;
  __syncthreads();
  int cur = 0;
#pragma unroll
  for (int d = 1; d < 256; d <<= 1) {
    int xv = buf[cur][tid];
    if (tid >= d) xv += buf[cur][tid - d];
    buf[cur ^ 1][tid] = xv;
    cur ^= 1;
    __syncthreads();
  }
  int incl = buf[cur][tid];
  if (i < N_) offs[i] = incl - v;
  if (tid == 255) partials[blockIdx.x] = incl;
}

__global__ __launch_bounds__(256) void scan2(int* __restrict__ partials, int* __restrict__ offs,
                                             int nb, int N_) {
  __shared__ int buf[2][256];
  int tid = threadIdx.x;
  int v = (tid < nb) ? partials[tid] : 0;
  buf[0][tid] = v;
  __syncthreads();
  int cur = 0;
#pragma unroll
  for (int d = 1; d < 256; d <<= 1) {
    int xv = buf[cur][tid];
    if (tid >= d) xv += buf[cur][tid - d];
    buf[cur ^ 1][tid] = xv;
    cur ^= 1;
    __syncthreads();
  }
  int incl = buf[cur][tid];
  if (tid < nb) partials[tid] = incl - v;
  if (tid == 255) offs[N_] = incl;
}

__global__ void scan3(int* __restrict__ offs, const int* __restrict__ partials, int N_) {
  int i = blockIdx.x * 256 + threadIdx.x;
  if (i < N_) offs[i] += partials[blockIdx.x];
}

__global__ void fill_csr(const int* __restrict__ ei, const int* __restrict__ offs,
                         int* __restrict__ cursor, int* __restrict__ csr, int E_, int N_) {
  int i = blockIdx.x * 256 + threadIdx.x;
  int s, d;
  if (i < E_) { s = ei[i]; d = ei[E_ + i]; }
  else if (i < E_ + N_) { s = d = i - E_; }
  else return;
  int pos = offs[d] + atomicAdd(&cursor[d], 1);
  csr[pos] = s;
}

// ---------------- graph ranges ----------------
__global__ void graph_ranges(const int* __restrict__ bids, int* __restrict__ gstart,
                             float* __restrict__ invcnt, int N_, int G_) {
  int t = threadIdx.x;
  if (t <= G_) {
    int lo = 0, hi = N_;
    while (lo < hi) { int mid = (lo + hi) >> 1; if (bids[mid] < t) lo = mid + 1; else hi = mid; }
    gstart[t] = lo;
  }
  __syncthreads();
  if (t < G_) {
    int c = gstart[t + 1] - gstart[t];
    invcnt[t] = (c > 0) ? 1.f / (float)c : 0.f;
  }
}

// ---------------- bf16 MFMA GEMM: C[M,Ncols] bf16 = A[M,K]bf16 @ B'[Ncols,K]^T + bias
__global__ __launch_bounds__(256) void gemm_bf16(
    const unsigned short* __restrict__ A, const unsigned short* __restrict__ Bp,
    const float* __restrict__ bias, unsigned short* __restrict__ C, int M, int K, int Ncols) {
  __shared__ unsigned short As[128 * 40];
  __shared__ unsigned short Bs[128 * 40];
  int tid = threadIdx.x;
  int lane = tid & 63;
  int wid = tid >> 6;
  int rowBase = blockIdx.y * 128, colBase = blockIdx.x * 128;
  int wr = (wid >> 1) * 64, wc = (wid & 1) * 64;
  int fr = lane & 15, fg = lane >> 4;
  float4v acc[4][4];
#pragma unroll
  for (int i = 0; i < 4; ++i)
#pragma unroll
    for (int j = 0; j < 4; ++j) acc[i][j] = (float4v){0.f, 0.f, 0.f, 0.f};

  int sr = tid >> 2;
  int sc = tid & 3;
  int off_lo = (sc < 2) ? 32 * sc : 32 * sc - 56;

  for (int k0 = 0; k0 < K; k0 += 32) {
#pragma unroll
    for (int it = 0; it < 2; ++it) {
      int r = it * 64 + sr;
      uint4 va = make_uint4(0u, 0u, 0u, 0u);
      if (rowBase + r < M)
        va = *(const uint4*)(A + (size_t)(rowBase + r) * K + k0 + sc * 8);
      char* arow = (char*)(As + r * 40);
      *(uint2*)(arow + off_lo) = make_uint2(va.x, va.y);
      *(uint2*)(arow + off_lo + 16) = make_uint2(va.z, va.w);
      uint4 vb = *(const uint4*)(Bp + (size_t)(colBase + r) * K + k0 + sc * 8);
      char* brow = (char*)(Bs + r * 40);
      *(uint2*)(brow + off_lo) = make_uint2(vb.x, vb.y);
      *(uint2*)(brow + off_lo + 16) = make_uint2(vb.z, vb.w);
    }
    __syncthreads();
    short8v af[4], bfv[4];
#pragma unroll
    for (int i = 0; i < 4; ++i)
      af[i] = *(const short8v*)((const char*)As + (wr + 16 * i + fr) * 80 + fg * 16);
#pragma unroll
    for (int j = 0; j < 4; ++j)
      bfv[j] = *(const short8v*)((const char*)Bs + (wc + 16 * j + fr) * 80 + fg * 16);
#pragma unroll
    for (int i = 0; i < 4; ++i)
#pragma unroll
      for (int j = 0; j < 4; ++j)
        acc[i][j] = __builtin_amdgcn_mfma_f32_16x16x32_bf16(af[i], bfv[j], acc[i][j], 0, 0, 0);
    __syncthreads();
  }
#pragma unroll
  for (int j = 0; j < 4; ++j) {
    int gc = colBase + wc + 16 * j + fr;
    float bv = bias[gc];
#pragma unroll
    for (int i = 0; i < 4; ++i) {
      int gr0 = rowBase + wr + 16 * i + fg * 4;
#pragma unroll
      for (int rg = 0; rg < 4; ++rg) {
        int gr = gr0 + rg;
        if (gr < M) C[(size_t)gr * Ncols + gc] = f2bf(acc[i][j][rg] + bv);
      }
    }
  }
}

// ---------------- GATv2 aggregation: 1 wave/node, 4 edges in flight, per-head softmax ----
// 16 lanes/edge, 8 ch/lane; a head (32 ch) spans 4 aligned lanes -> reduce is xor 1,2 ONLY.
// Merge the 4 edge-slot states via xor 16,32. (8-edge variant regressed: deg~17 makes the
// 4-stage/16-ch merge dominate — measured r10.)
// Also zeroes gsum+gsq (64KB) in the first 16 blocks (safe: prior layer's gn_apply done).
__global__ __launch_bounds__(256) void gat_agg(
    const unsigned short* __restrict__ xlr, int stride,
    const int* __restrict__ csr, const int* __restrict__ offs,
    const float* __restrict__ att, const float* __restrict__ bias,
    unsigned short* __restrict__ out, float* __restrict__ gz, int N) {
  int zt = blockIdx.x * 256 + threadIdx.x;
  if (zt < 4096) *(float4*)(gz + zt * 4) = make_float4(0.f, 0.f, 0.f, 0.f);
  int wid = zt >> 6;
  if (wid >= N) return;
  int lane = threadIdx.x & 63;
  int q = lane >> 4, ql = lane & 15;   // edge slot, channel group (8 ch each)
  float4 aA = *(const float4*)&att[ql * 8];
  float4 aB = *(const float4*)&att[ql * 8 + 4];
  uint4 ur = *(const uint4*)(xlr + (size_t)wid * stride + 128 + ql * 8);
  float r0 = bflo(ur.x), r1 = bfhi(ur.x), r2 = bflo(ur.y), r3 = bfhi(ur.y);
  float r4 = bflo(ur.z), r5 = bfhi(ur.z), r6 = bflo(ur.w), r7 = bfhi(ur.w);
  float m = -1e30f, L = 0.f;
  float s0 = 0.f, s1 = 0.f, s2 = 0.f, s3 = 0.f, s4 = 0.f, s5 = 0.f, s6 = 0.f, s7 = 0.f;
  int js = offs[wid], je = offs[wid + 1];
  for (int j = js + q; j < je; j += 4) {
    int s = csr[j];
    uint4 u = *(const uint4*)(xlr + (size_t)s * stride + ql * 8);
    float x0 = bflo(u.x), x1 = bfhi(u.x), x2 = bflo(u.y), x3 = bfhi(u.y);
    float x4 = bflo(u.z), x5 = bfhi(u.z), x6 = bflo(u.w), x7 = bfhi(u.w);
    float v0 = fmaxf(r0 + x0, 0.2f * (r0 + x0));
    float v1 = fmaxf(r1 + x1, 0.2f * (r1 + x1));
    float v2 = fmaxf(r2 + x2, 0.2f * (r2 + x2));
    float v3 = fmaxf(r3 + x3, 0.2f * (r3 + x3));
    float v4 = fmaxf(r4 + x4, 0.2f * (r4 + x4));
    float v5 = fmaxf(r5 + x5, 0.2f * (r5 + x5));
    float v6 = fmaxf(r6 + x6, 0.2f * (r6 + x6));
    float v7 = fmaxf(r7 + x7, 0.2f * (r7 + x7));
    float p = aA.x * v0 + aA.y * v1 + aA.z * v2 + aA.w * v3 +
              aB.x * v4 + aB.y * v5 + aB.z * v6 + aB.w * v7;
    p += __shfl_xor(p, 1); p += __shfl_xor(p, 2);   // per-head reduce (4 lanes = 32 ch)
    float mn = fmaxf(m, p);
    float ea = __expf(p - mn);
    float es = __expf(m - mn);
    L = L * es + ea;
    s0 = s0 * es + ea * x0; s1 = s1 * es + ea * x1;
    s2 = s2 * es + ea * x2; s3 = s3 * es + ea * x3;
    s4 = s4 * es + ea * x4; s5 = s5 * es + ea * x5;
    s6 = s6 * es + ea * x6; s7 = s7 * es + ea * x7;
    m = mn;
  }
  // merge the 4 edge-slot states (per head/channel-slice)
#pragma unroll
  for (int d = 16; d <= 32; d <<= 1) {
    float mo = __shfl_xor(m, d), Lo = __shfl_xor(L, d);
    float t0 = __shfl_xor(s0, d), t1 = __shfl_xor(s1, d);
    float t2 = __shfl_xor(s2, d), t3 = __shfl_xor(s3, d);
    float t4 = __shfl_xor(s4, d), t5 = __shfl_xor(s5, d);
    float t6 = __shfl_xor(s6, d), t7 = __shfl_xor(s7, d);
    float mn = fmaxf(m, mo);
    float e0 = __expf(m - mn), e1 = __expf(mo - mn);
    L = L * e0 + Lo * e1;
    s0 = s0 * e0 + t0 * e1; s1 = s1 * e0 + t1 * e1;
    s2 = s2 * e0 + t2 * e1; s3 = s3 * e0 + t3 * e1;
    s4 = s4 * e0 + t4 * e1; s5 = s5 * e0 + t5 * e1;
    s6 = s6 * e0 + t6 * e1; s7 = s7 * e0 + t7 * e1;
    m = mn;
  }
  if (q == 0) {
    float inv = 1.f / L;
    float4 bA = *(const float4*)&bias[ql * 8];
    float4 bB = *(const float4*)&bias[ql * 8 + 4];
    uint4 ov;
    ov.x = bfpack(s0 * inv + bA.x, s1 * inv + bA.y);
    ov.y = bfpack(s2 * inv + bA.z, s3 * inv + bA.w);
    ov.z = bfpack(s4 * inv + bB.x, s5 * inv + bB.y);
    ov.w = bfpack(s6 * inv + bB.z, s7 * inv + bB.w);
    *(uint4*)(out + (size_t)wid * DD + ql * 8) = ov;
  }
}

// ---------------- GraphNorm stats (bf16 input, uint-vectorized) ----------------
__global__ __launch_bounds__(256) void gn_stats2(const unsigned short* __restrict__ x,
                                                 const int* __restrict__ bids,
                                                 float* __restrict__ gsum,
                                                 float* __restrict__ gsq, int N) {
  int base = blockIdx.x * 128;
  int cp = threadIdx.x & 63;   // channel pair
  int sub = threadIdx.x >> 6;  // row offset 0..3
  int end = base + 128 < N ? base + 128 : N;
  int curg = -1;
  float s0 = 0.f, s1 = 0.f, q0 = 0.f, q1 = 0.f;
  for (int r = base + sub; r < end; r += 4) {
    int g = bids[r];
    if (g != curg) {
      if (curg >= 0) {
        atomicAdd(&gsum[curg * DD + cp * 2], s0);
        atomicAdd(&gsum[curg * DD + cp * 2 + 1], s1);
        atomicAdd(&gsq[curg * DD + cp * 2], q0);
        atomicAdd(&gsq[curg * DD + cp * 2 + 1], q1);
      }
      curg = g; s0 = s1 = q0 = q1 = 0.f;
    }
    uint32_t u = *(const uint32_t*)(x + (size_t)r * DD + cp * 2);
    float v0 = bflo(u), v1 = bfhi(u);
    s0 += v0; q0 += v0 * v0; s1 += v1; q1 += v1 * v1;
  }
  if (curg >= 0) {
    atomicAdd(&gsum[curg * DD + cp * 2], s0);
    atomicAdd(&gsum[curg * DD + cp * 2 + 1], s1);
    atomicAdd(&gsq[curg * DD + cp * 2], q0);
    atomicAdd(&gsq[curg * DD + cp * 2 + 1], q1);
  }
}

// ---------------- GraphNorm apply + ELU (+residual) : bf16 in -> bf16 out --------------
template <bool ADDRES>
__global__ void gn_apply(const unsigned short* __restrict__ xin,
                         unsigned short* __restrict__ xout,
                         const unsigned short* __restrict__ res, int resStride,
                         const int* __restrict__ bids, const float* __restrict__ gsum,
                         const float* __restrict__ gsq, const float* __restrict__ invcnt,
                         const float* __restrict__ w, const float* __restrict__ b,
                         const float* __restrict__ ms, int N) {
  int idx = blockIdx.x * 256 + threadIdx.x;
  if (idx >= N * 64) return;
  int n = idx >> 6, cp = idx & 63;
  int g = bids[n];
  float ic = invcnt[g];
  float2 sm = *(const float2*)&gsum[g * DD + cp * 2];
  float2 sq = *(const float2*)&gsq[g * DD + cp * 2];
  float2 w2 = *(const float2*)&w[cp * 2];
  float2 b2 = *(const float2*)&b[cp * 2];
  float2 m2 = *(const float2*)&ms[cp * 2];
  uint32_t u = *(const uint32_t*)(xin + (size_t)n * DD + cp * 2);
  float mean0 = sm.x * ic, mean1 = sm.y * ic;
  float mm0 = mean0 * m2.x, mm1 = mean1 * m2.y;
  float var0 = sq.x * ic - mm0 * (2.f * mean0 - mm0);
  float var1 = sq.y * ic - mm1 * (2.f * mean1 - mm1);
  float v0 = (bflo(u) - mm0) * rsqrtf(var0 + 1e-5f) * w2.x + b2.x;
  float v1 = (bfhi(u) - mm1) * rsqrtf(var1 + 1e-5f) * w2.y + b2.y;
  if (ADDRES) {
    uint32_t ur = *(const uint32_t*)(res + (size_t)n * resStride + cp * 2);
    v0 += bflo(ur); v1 += bfhi(ur);
  }
  v0 = v0 > 0.f ? v0 : (__expf(v0) - 1.f);
  v1 = v1 > 0.f ? v1 : (__expf(v1) - 1.f);
  *(uint32_t*)(xout + (size_t)n * DD + cp * 2) = bfpack(v0, v1);
}

// ---------------- LSTM step: barrier-free, operands direct from L2 ----------------
// MFMA k-permutation invariance: lane (fr,fg) takes k = k0 + fg*8..+8 for BOTH A and W,
// so each fragment is ONE contiguous 16B global load (L2-resident: A panel is XCD-local
// via swizzle, W is 0.5MB hot). No LDS staging, no K-loop barriers — waves free-run.
// Block: 256 thr (4 waves = 2 row x 2 col), 128 rows x 32 h-channels; f-gate dead (c0=0).
// LDS only for the H-transpose epilogue (10.2KB). OOB rows read in-workspace garbage,
// masked at store. (256,4): r11 showed tighter VGPR caps spill.
template <int KD>
__global__ __launch_bounds__(256, 4) void lstm_big(
    const unsigned short* __restrict__ A, const unsigned short* __restrict__ Bp,
    const float* __restrict__ bsum, unsigned short* __restrict__ H, int M) {
  __shared__ unsigned short Hs[128 * 40];
  int npanel = (M + 127) >> 7;
  int b = blockIdx.x;
  int g8 = b & 7, inner = b >> 3;
  int p = g8 + 8 * (inner >> 3);
  int cc = inner & 7;
  if (p >= npanel) return;
  int rowBase = p << 7;
  int ch0 = cc * 32;

  int tid = threadIdx.x;
  int lane = tid & 63;
  int wid = tid >> 6;
  int wr2 = wid >> 1;   // 0..1 row-group (64 rows)
  int wc2 = wid & 1;    // 0..1 col-group (16 ch)
  int fr = lane & 15, fg = lane >> 4;

  const unsigned short* abase = A + (size_t)(rowBase + 64 * wr2 + fr) * KD + fg * 8;
  int wrow = ch0 + 16 * wc2 + fr;
  const unsigned short* wb0 = Bp + (size_t)(wrow) * KD + fg * 8;        // i gate
  const unsigned short* wb1 = Bp + (size_t)(512 + wrow) * KD + fg * 8;  // g gate
  const unsigned short* wb2 = Bp + (size_t)(768 + wrow) * KD + fg * 8;  // o gate

  float4v acc[4][3];
#pragma unroll
  for (int i = 0; i < 4; ++i)
#pragma unroll
    for (int j = 0; j < 3; ++j) acc[i][j] = (float4v){0.f, 0.f, 0.f, 0.f};

#pragma unroll
  for (int k0 = 0; k0 < KD; k0 += 32) {
    short8v af[4], bf[3];
#pragma unroll
    for (int i = 0; i < 4; ++i)
      af[i] = *(const short8v*)(abase + (size_t)(16 * i) * KD + k0);
    bf[0] = *(const short8v*)(wb0 + k0);
    bf[1] = *(const short8v*)(wb1 + k0);
    bf[2] = *(const short8v*)(wb2 + k0);
#pragma unroll
    for (int i = 0; i < 4; ++i)
#pragma unroll
      for (int j = 0; j < 3; ++j)
        acc[i][j] = __builtin_amdgcn_mfma_f32_16x16x32_bf16(af[i], bf[j], acc[i][j], 0, 0, 0);
  }
  // epilogue: lane owns channel ch for 16 rows; activations in registers
  int chL = 16 * wc2 + fr;
  int ch = ch0 + chL;
  float bi = bsum[ch], bg = bsum[512 + ch], bo = bsum[768 + ch];
#pragma unroll
  for (int i = 0; i < 4; ++i) {
#pragma unroll
    for (int rg = 0; rg < 4; ++rg) {
      float iv = acc[i][0][rg] + bi;
      float gv = acc[i][1][rg] + bg;
      float ov = acc[i][2][rg] + bo;
      float c = sigm_(iv) * tanh_(gv);
      int row = 64 * wr2 + 16 * i + 4 * fg + rg;
      Hs[row * 40 + chL] = f2bf(sigm_(ov) * tanh_(c));
    }
  }
  __syncthreads();
#pragma unroll
  for (int q = 0; q < 2; ++q) {
    int e = q * 256 + tid;
    int row = e >> 2, seg = e & 3;
    if (rowBase + row < M) {
      uint4 v = *(const uint4*)(Hs + row * 40 + seg * 8);
      *(uint4*)(H + (size_t)(rowBase + row) * LSTMH + ch0 + seg * 8) = v;
    }
  }
}

// ---------------- LayerNorm + mean pool: 1 wave per 8 rows, register pooling ----------
__global__ __launch_bounds__(256) void ln_pool2(
    const unsigned short* __restrict__ h2, const int* __restrict__ bids,
    const float* __restrict__ lnw, const float* __restrict__ lnb,
    const float* __restrict__ invcnt, float* __restrict__ pooled, int N) {
  int wave = (blockIdx.x * 256 + threadIdx.x) >> 6;
  int lane = threadIdx.x & 63;
  int r0 = wave * 8;
  if (r0 >= N) return;
  float4 w4 = *(const float4*)&lnw[lane * 4];
  float4 b4 = *(const float4*)&lnb[lane * 4];
  float p0 = 0.f, p1 = 0.f, p2 = 0.f, p3 = 0.f;
  int curg = bids[r0];
  int rend = r0 + 8 < N ? r0 + 8 : N;
  for (int r = r0; r < rend; ++r) {
    int g = bids[r];
    if (g != curg) {
      float ic = invcnt[curg];
      atomicAdd(&pooled[curg * LSTMH + lane * 4 + 0], p0 * ic);
      atomicAdd(&pooled[curg * LSTMH + lane * 4 + 1], p1 * ic);
      atomicAdd(&pooled[curg * LSTMH + lane * 4 + 2], p2 * ic);
      atomicAdd(&pooled[curg * LSTMH + lane * 4 + 3], p3 * ic);
      p0 = p1 = p2 = p3 = 0.f;
      curg = g;
    }
    uint2 u = *(const uint2*)(h2 + (size_t)r * LSTMH + lane * 4);
    float v0 = bflo(u.x), v1 = bfhi(u.x), v2 = bflo(u.y), v3 = bfhi(u.y);
    float s = v0 + v1 + v2 + v3;
    float q = v0 * v0 + v1 * v1 + v2 * v2 + v3 * v3;
#pragma unroll
    for (int d = 1; d < 64; d <<= 1) { s += __shfl_xor(s, d); q += __shfl_xor(q, d); }
    float mu = s * (1.f / 256.f);
    float var = q * (1.f / 256.f) - mu * mu;
    float rs = rsqrtf(var + 1e-5f);
    p0 += w4.x * (v0 - mu) * rs + b4.x;
    p1 += w4.y * (v1 - mu) * rs + b4.y;
    p2 += w4.z * (v2 - mu) * rs + b4.z;
    p3 += w4.w * (v3 - mu) * rs + b4.w;
  }
  float ic = invcnt[curg];
  atomicAdd(&pooled[curg * LSTMH + lane * 4 + 0], p0 * ic);
  atomicAdd(&pooled[curg * LSTMH + lane * 4 + 1], p1 * ic);
  atomicAdd(&pooled[curg * LSTMH + lane * 4 + 2], p2 * ic);
  atomicAdd(&pooled[curg * LSTMH + lane * 4 + 3], p3 * ic);
}

// ---------------- FC + log_softmax ----------------
__global__ __launch_bounds__(64) void fc_lsm(const float* __restrict__ pooled,
                                             const float* __restrict__ W,
                                             const float* __restrict__ b, float* __restrict__ out) {
  int g = blockIdx.x;
  int t = threadIdx.x;
  float l0 = 0.f, l1 = 0.f, l2 = 0.f, l3 = 0.f;
  for (int k = t; k < LSTMH; k += 64) {
    float p = pooled[g * LSTMH + k];
    l0 += p * W[k * 4 + 0];
    l1 += p * W[k * 4 + 1];
    l2 += p * W[k * 4 + 2];
    l3 += p * W[k * 4 + 3];
  }
#pragma unroll
  for (int d = 1; d < 64; d <<= 1) {
    l0 += __shfl_xor(l0, d); l1 += __shfl_xor(l1, d);
    l2 += __shfl_xor(l2, d); l3 += __shfl_xor(l3, d);
  }
  if (t == 0) {
    float z[4] = {l0 + b[0], l1 + b[1], l2 + b[2], l3 + b[3]};
    float mx = fmaxf(fmaxf(z[0], z[1]), fmaxf(z[2], z[3]));
    float sum = __expf(z[0] - mx) + __expf(z[1] - mx) + __expf(z[2] - mx) + __expf(z[3] - mx);
    float ls = logf(sum);
#pragma unroll
    for (int o = 0; o < 4; ++o) out[g * 4 + o] = z[o] - mx - ls;
  }
}

// ---------------- host launch ----------------
extern "C" void kernel_launch(void* const* d_in, const int* in_sizes, int n_in,
                              void* d_out, int out_size, void* d_ws, size_t ws_size,
                              hipStream_t stream) {
  const int* node_labels = (const int*)d_in[0];
  const int* node_types = (const int*)d_in[1];
  const float* node_feat = (const float*)d_in[2];
  const int* edge_index = (const int*)d_in[3];
  const int* batch_ids = (const int*)d_in[4];
  const float* emb_label = (const float*)d_in[5];
  const float* emb_type = (const float*)d_in[6];
  const float* W_in = (const float*)d_in[7];
  const float* b_in = (const float*)d_in[8];
  const float* g1_Wl = (const float*)d_in[9];
  const float* g1_bl = (const float*)d_in[10];
  const float* g1_Wr = (const float*)d_in[11];
  const float* g1_br = (const float*)d_in[12];
  const float* g1_att = (const float*)d_in[13];
  const float* g1_bias = (const float*)d_in[14];
  const float* gn1_w = (const float*)d_in[15];
  const float* gn1_b = (const float*)d_in[16];
  const float* gn1_ms = (const float*)d_in[17];
  const float* g2_Wl = (const float*)d_in[18];
  const float* g2_bl = (const float*)d_in[19];
  const float* g2_Wr = (const float*)d_in[20];
  const float* g2_br = (const float*)d_in[21];
  const float* g2_att = (const float*)d_in[22];
  const float* g2_bias = (const float*)d_in[23];
  const float* gn2_w = (const float*)d_in[24];
  const float* gn2_b = (const float*)d_in[25];
  const float* gn2_ms = (const float*)d_in[26];
  const float* W_res = (const float*)d_in[27];
  const float* b_res = (const float*)d_in[28];
  const float* l1_Wih = (const float*)d_in[29];
  const float* l1_bih = (const float*)d_in[31];
  const float* l1_bhh = (const float*)d_in[32];
  const float* l2_Wih = (const float*)d_in[33];
  const float* l2_bih = (const float*)d_in[35];
  const float* l2_bhh = (const float*)d_in[36];
  const float* ln_w = (const float*)d_in[37];
  const float* ln_b = (const float*)d_in[38];
  const float* fc_W = (const float*)d_in[39];
  const float* fc_b = (const float*)d_in[40];
  float* out = (float*)d_out;

  const int N = in_sizes[0];
  const int E = in_sizes[3] / 2;
  const int G = out_size / 4;
  const int ET = E + N;

  char* wsb = (char*)d_ws;
  size_t off = 0;
  auto alloc = [&](size_t bytes) -> void* {
    void* p = (void*)(wsb + off);
    off = (off + bytes + 255) & ~(size_t)255;
    return p;
  };
  unsigned short* xA = (unsigned short*)alloc((size_t)N * 512);       // gat out bf16; later h2
  unsigned short* xb = (unsigned short*)alloc((size_t)N * DD * 2);    // bf16 x / x1 / x2
  unsigned short* xlr = (unsigned short*)alloc((size_t)N * 384 * 2);  // xl|xr(|res); later h1
  int* deg = (int*)alloc((size_t)N * 4);
  int* offs = (int*)alloc((size_t)(N + 1) * 4);
  int* cursor = (int*)alloc((size_t)N * 4);
  int* partials = (int*)alloc(1024);
  int* csr = (int*)alloc((size_t)ET * 4);
  int* gstart = (int*)alloc((size_t)(G + 1) * 4);
  float* invcnt = (float*)alloc((size_t)G * 4);
  float* gsum = (float*)alloc((size_t)G * DD * 4);   // contiguous with gsq (32KB each)
  float* gsq = (float*)alloc((size_t)G * DD * 4);
  float* pooled = (float*)alloc((size_t)G * LSTMH * 4);
  float* bcat1 = (float*)alloc(256 * 4);
  float* bcat2 = (float*)alloc(384 * 4);
  float* bsum1 = (float*)alloc(ZG * 4);
  float* bsum2 = (float*)alloc(ZG * 4);
  unsigned short* wcat1 = (unsigned short*)alloc((size_t)256 * DD * 2);
  unsigned short* wcat2 = (unsigned short*)alloc((size_t)384 * DD * 2);
  unsigned short* wl1b = (unsigned short*)alloc((size_t)ZG * DD * 2);
  unsigned short* wl2b = (unsigned short*)alloc((size_t)ZG * LSTMH * 2);
  (void)ws_size; (void)n_in;

  unsigned short* h1 = xlr;   // [N][256] bf16, written after xlr dead
  unsigned short* h2 = xA;    // [N][256] bf16, written after xA dead

  int prepTotal = 477824 + 2 * N + 16384;
  prep_all<<<cdiv_(prepTotal, 256), 256, 0, stream>>>(
      g1_Wl, g1_Wr, g2_Wl, g2_Wr, W_res, l1_Wih, l2_Wih,
      g1_bl, g1_br, g2_bl, g2_br, b_res, l1_bih, l1_bhh, l2_bih, l2_bhh,
      wcat1, wcat2, wl1b, wl2b, bcat1, bcat2, bsum1, bsum2,
      deg, cursor, pooled, N);
  graph_ranges<<<1, 128, 0, stream>>>(batch_ids, gstart, invcnt, N, G);
  embed_in2<<<cdiv_(N, 128), 256, 0, stream>>>(node_labels, node_types, node_feat, emb_label,
                                               emb_type, W_in, b_in, xb, N);

  // CSR by dst
  count_deg<<<cdiv_(ET, 256), 256, 0, stream>>>(edge_index, deg, E, N);
  int nb1 = cdiv_(N, 256);
  scan1<<<nb1, 256, 0, stream>>>(deg, offs, partials, N);
  scan2<<<1, 256, 0, stream>>>(partials, offs, nb1, N);
  scan3<<<nb1, 256, 0, stream>>>(offs, partials, N);
  fill_csr<<<cdiv_(ET, 256), 256, 0, stream>>>(edge_index, offs, cursor, csr, E, N);

  int mb = cdiv_(N, 128);
  // ---- GAT layer 1: [xl|xr] in one GEMM ----
  gemm_bf16<<<dim3(2, mb), 256, 0, stream>>>(xb, wcat1, bcat1, xlr, N, DD, 256);
  gat_agg<<<cdiv_(N, 4), 256, 0, stream>>>(xlr, 256, csr, offs, g1_att, g1_bias, xA, gsum, N);
  gn_stats2<<<cdiv_(N, 128), 256, 0, stream>>>(xA, batch_ids, gsum, gsq, N);
  gn_apply<false><<<cdiv_(N * 64, 256), 256, 0, stream>>>(
      xA, xb, nullptr, 0, batch_ids, gsum, gsq, invcnt, gn1_w, gn1_b, gn1_ms, N);
  // ---- GAT layer 2: [xl|xr|res] in one GEMM ----
  gemm_bf16<<<dim3(3, mb), 256, 0, stream>>>(xb, wcat2, bcat2, xlr, N, DD, 384);
  gat_agg<<<cdiv_(N, 4), 256, 0, stream>>>(xlr, 384, csr, offs, g2_att, g2_bias, xA, gsum, N);
  gn_stats2<<<cdiv_(N, 128), 256, 0, stream>>>(xA, batch_ids, gsum, gsq, N);
  gn_apply<true><<<cdiv_(N * 64, 256), 256, 0, stream>>>(
      xA, xb, xlr + 256, 384, batch_ids, gsum, gsq, invcnt, gn2_w, gn2_b, gn2_ms, N);
  // ---- LSTM x2: barrier-free L2-direct MFMA, XCD-swizzled ----
  int npanel = cdiv_(N, 128);
  int lblocks = 64 * cdiv_(npanel, 8);
  lstm_big<DD><<<lblocks, 256, 0, stream>>>(xb, wl1b, bsum1, h1, N);
  lstm_big<LSTMH><<<lblocks, 256, 0, stream>>>(h1, wl2b, bsum2, h2, N);
  // ---- LN + mean pool + FC ----
  ln_pool2<<<cdiv_(N, 32), 256, 0, stream>>>(h2, batch_ids, ln_w, ln_b, invcnt, pooled, N);
  fc_lsm<<<G, 64, 0, stream>>>(pooled, fc_W, fc_b, out);
}

// Round 14
// 483.127 us; speedup vs baseline: 1.0673x; 1.0673x over previous
//
#include <hip/hip_runtime.h>
#include <cstdint>
#include <cstddef>

#define DD 128
#define LSTMH 256
#define ZG 1024

typedef __attribute__((ext_vector_type(8))) short short8v;
typedef __attribute__((ext_vector_type(4))) float float4v;

static inline int cdiv_(int a, int b) { return (a + b - 1) / b; }

__device__ __forceinline__ float sigm_(float x) { return 1.f / (1.f + __expf(-x)); }
__device__ __forceinline__ float tanh_(float x) {
  float e = __expf(-2.f * fabsf(x));
  float r = (1.f - e) / (1.f + e);
  return copysignf(r, x);
}

__device__ __forceinline__ unsigned short f2bf(float f) {
  uint32_t u = __float_as_uint(f);
  u += 0x7fffu + ((u >> 16) & 1u);
  return (unsigned short)(u >> 16);
}
__device__ __forceinline__ uint32_t bfpack(float a, float b) {
  return (uint32_t)f2bf(a) | ((uint32_t)f2bf(b) << 16);
}
__device__ __forceinline__ float bflo(uint32_t u) { return __uint_as_float(u << 16); }
__device__ __forceinline__ float bfhi(uint32_t u) { return __uint_as_float(u & 0xffff0000u); }

// ------- fused prep: 5 transposes + 2 casts + biases + deg/cursor/pooled zero, 1 launch --
__global__ void prep_all(const float* __restrict__ g1Wl, const float* __restrict__ g1Wr,
                         const float* __restrict__ g2Wl, const float* __restrict__ g2Wr,
                         const float* __restrict__ Wres, const float* __restrict__ l1Wih,
                         const float* __restrict__ l2Wih, const float* __restrict__ g1bl,
                         const float* __restrict__ g1br, const float* __restrict__ g2bl,
                         const float* __restrict__ g2br, const float* __restrict__ bres,
                         const float* __restrict__ l1bih, const float* __restrict__ l1bhh,
                         const float* __restrict__ l2bih, const float* __restrict__ l2bhh,
                         unsigned short* __restrict__ wcat1, unsigned short* __restrict__ wcat2,
                         unsigned short* __restrict__ wl1b, unsigned short* __restrict__ wl2b,
                         float* __restrict__ bcat1, float* __restrict__ bcat2,
                         float* __restrict__ bsum1, float* __restrict__ bsum2,
                         int* __restrict__ deg, int* __restrict__ cursor,
                         float* __restrict__ pooled, int Nn) {
  int i = blockIdx.x * 256 + threadIdx.x;
  if (i < 81920) {  // five 128x128 transposes -> [M][K] bf16
    int seg = i >> 14, j = i & 16383;
    int m = j >> 7, k = j & 127;
    const float* src = (seg == 0) ? g1Wl : (seg == 1) ? g1Wr : (seg == 2) ? g2Wl
                       : (seg == 3) ? g2Wr : Wres;
    unsigned short* dst = (seg == 0) ? wcat1 : (seg == 1) ? wcat1 + 16384
                          : (seg == 2) ? wcat2 : (seg == 3) ? wcat2 + 16384 : wcat2 + 32768;
    dst[j] = f2bf(src[k * 128 + m]);
    return;
  }
  i -= 81920;
  if (i < 131072) { wl1b[i] = f2bf(l1Wih[i]); return; }
  i -= 131072;
  if (i < 262144) { wl2b[i] = f2bf(l2Wih[i]); return; }
  i -= 262144;
  if (i < 256) { bcat1[i] = (i < 128) ? g1bl[i] : g1br[i - 128]; return; }
  i -= 256;
  if (i < 384) {
    bcat2[i] = (i < 128) ? g2bl[i] : (i < 256 ? g2br[i - 128] : bres[i - 256]);
    return;
  }
  i -= 384;
  if (i < 1024) { bsum1[i] = l1bih[i] + l1bhh[i]; return; }
  i -= 1024;
  if (i < 1024) { bsum2[i] = l2bih[i] + l2bhh[i]; return; }
  i -= 1024;
  if (i < Nn) { deg[i] = 0; return; }
  i -= Nn;
  if (i < Nn) { cursor[i] = 0; return; }
  i -= Nn;
  if (i < 16384) { pooled[i] = 0.f; return; }
}

// ---------------- embedding + W_in GEMV: 128 nodes/block, W in registers ----------------
__global__ __launch_bounds__(256) void embed_in2(
    const int* __restrict__ labels, const int* __restrict__ types,
    const float* __restrict__ nf, const float* __restrict__ embL,
    const float* __restrict__ embT, const float* __restrict__ W,
    const float* __restrict__ b, unsigned short* __restrict__ x, int N) {
  __shared__ float f[128][34];
  int base = blockIdx.x * 128;
  int tid = threadIdx.x;
  int ch = tid & 127, half = tid >> 7;
  float wr[33];
#pragma unroll
  for (int k = 0; k < 33; ++k) wr[k] = W[k * 128 + ch];
  float bb = b[ch];
  int nmax = N - base < 128 ? N - base : 128;
  for (int e = tid; e < nmax * 32; e += 256) {
    int n = e >> 5, k = e & 31;
    f[n][k] = (k < 16) ? embL[labels[base + n] * 16 + k] : embT[types[base + n] * 16 + (k - 16)];
  }
  for (int n = tid; n < nmax; n += 256) f[n][32] = nf[base + n];
  __syncthreads();
  for (int n = half; n < nmax; n += 2) {
    float acc = bb;
#pragma unroll
    for (int k = 0; k < 33; ++k) acc = fmaf(f[n][k], wr[k], acc);
    x[(size_t)(base + n) * 128 + ch] = f2bf(acc);
  }
}

// ---------------- CSR build ----------------
__global__ void count_deg(const int* __restrict__ ei, int* __restrict__ deg, int E_, int N_) {
  int i = blockIdx.x * 256 + threadIdx.x;
  if (i < E_) atomicAdd(&deg[ei[E_ + i]], 1);
  else if (i < E_ + N_) atomicAdd(&deg[i - E_], 1);
}

__global__ __launch_bounds__(256) void scan1(const int* __restrict__ deg, int* __restrict__ offs,
                                             int* __restrict__ partials, int N_) {
  __shared__ int buf[2][256];
  int tid = threadIdx.x;
  int i = blockIdx.x * 256 + tid;
  int v = (i < N_) ? deg[i] : 0;
  buf[0][tid] = v;
  __syncthreads();
  int cur = 0;
#pragma unroll
  for (int d = 1; d < 256; d <<= 1) {
    int xv = buf[cur][tid];
    if (tid >= d) xv += buf[cur][tid - d];
    buf[cur ^ 1][tid] = xv;
    cur ^= 1;
    __syncthreads();
  }
  int incl = buf[cur][tid];
  if (i < N_) offs[i] = incl - v;
  if (tid == 255) partials[blockIdx.x] = incl;
}

__global__ __launch_bounds__(256) void scan2(int* __restrict__ partials, int* __restrict__ offs,
                                             int nb, int N_) {
  __shared__ int buf[2][256];
  int tid = threadIdx.x;
  int v = (tid < nb) ? partials[tid] : 0;
  buf[0][tid] = v;
  __syncthreads();
  int cur = 0;
#pragma unroll
  for (int d = 1; d < 256; d <<= 1) {
    int xv = buf[cur][tid];
    if (tid >= d) xv += buf[cur][tid - d];
    buf[cur ^ 1][tid] = xv;
    cur ^= 1;
    __syncthreads();
  }
  int incl = buf[cur][tid];
  if (tid < nb) partials[tid] = incl - v;
  if (tid == 255) offs[N_] = incl;
}

__global__ void scan3(int* __restrict__ offs, const int* __restrict__ partials, int N_) {
  int i = blockIdx.x * 256 + threadIdx.x;
  if (i < N_) offs[i] += partials[blockIdx.x];
}

__global__ void fill_csr(const int* __restrict__ ei, const int* __restrict__ offs,
                         int* __restrict__ cursor, int* __restrict__ csr, int E_, int N_) {
  int i = blockIdx.x * 256 + threadIdx.x;
  int s, d;
  if (i < E_) { s = ei[i]; d = ei[E_ + i]; }
  else if (i < E_ + N_) { s = d = i - E_; }
  else return;
  int pos = offs[d] + atomicAdd(&cursor[d], 1);
  csr[pos] = s;
}

// ---------------- graph ranges ----------------
__global__ void graph_ranges(const int* __restrict__ bids, int* __restrict__ gstart,
                             float* __restrict__ invcnt, int N_, int G_) {
  int t = threadIdx.x;
  if (t <= G_) {
    int lo = 0, hi = N_;
    while (lo < hi) { int mid = (lo + hi) >> 1; if (bids[mid] < t) lo = mid + 1; else hi = mid; }
    gstart[t] = lo;
  }
  __syncthreads();
  if (t < G_) {
    int c = gstart[t + 1] - gstart[t];
    invcnt[t] = (c > 0) ? 1.f / (float)c : 0.f;
  }
}

// ---------------- bf16 MFMA GEMM: C[M,Ncols] bf16 = A[M,K]bf16 @ B'[Ncols,K]^T + bias
// Linear k-layout in LDS (k-permutation invariance): one uint4 store per staged unit;
// fragment k = fg*8..+8, identical mapping for A and B.
__global__ __launch_bounds__(256) void gemm_bf16(
    const unsigned short* __restrict__ A, const unsigned short* __restrict__ Bp,
    const float* __restrict__ bias, unsigned short* __restrict__ C, int M, int K, int Ncols) {
  __shared__ __attribute__((aligned(16))) unsigned short As[128 * 40];
  __shared__ __attribute__((aligned(16))) unsigned short Bs[128 * 40];
  int tid = threadIdx.x;
  int lane = tid & 63;
  int wid = tid >> 6;
  int rowBase = blockIdx.y * 128, colBase = blockIdx.x * 128;
  int wr = (wid >> 1) * 64, wc = (wid & 1) * 64;
  int fr = lane & 15, fg = lane >> 4;
  float4v acc[4][4];
#pragma unroll
  for (int i = 0; i < 4; ++i)
#pragma unroll
    for (int j = 0; j < 4; ++j) acc[i][j] = (float4v){0.f, 0.f, 0.f, 0.f};

  int sr = tid >> 2;
  int sc = tid & 3;

  for (int k0 = 0; k0 < K; k0 += 32) {
#pragma unroll
    for (int it = 0; it < 2; ++it) {
      int r = it * 64 + sr;
      uint4 va = make_uint4(0u, 0u, 0u, 0u);
      if (rowBase + r < M)
        va = *(const uint4*)(A + (size_t)(rowBase + r) * K + k0 + sc * 8);
      *(uint4*)((char*)As + r * 80 + sc * 16) = va;
      uint4 vb = *(const uint4*)(Bp + (size_t)(colBase + r) * K + k0 + sc * 8);
      *(uint4*)((char*)Bs + r * 80 + sc * 16) = vb;
    }
    __syncthreads();
    short8v af[4], bfv[4];
#pragma unroll
    for (int i = 0; i < 4; ++i)
      af[i] = *(const short8v*)((const char*)As + (wr + 16 * i + fr) * 80 + fg * 16);
#pragma unroll
    for (int j = 0; j < 4; ++j)
      bfv[j] = *(const short8v*)((const char*)Bs + (wc + 16 * j + fr) * 80 + fg * 16);
#pragma unroll
    for (int i = 0; i < 4; ++i)
#pragma unroll
      for (int j = 0; j < 4; ++j)
        acc[i][j] = __builtin_amdgcn_mfma_f32_16x16x32_bf16(af[i], bfv[j], acc[i][j], 0, 0, 0);
    __syncthreads();
  }
#pragma unroll
  for (int j = 0; j < 4; ++j) {
    int gc = colBase + wc + 16 * j + fr;
    float bv = bias[gc];
#pragma unroll
    for (int i = 0; i < 4; ++i) {
      int gr0 = rowBase + wr + 16 * i + fg * 4;
#pragma unroll
      for (int rg = 0; rg < 4; ++rg) {
        int gr = gr0 + rg;
        if (gr < M) C[(size_t)gr * Ncols + gc] = f2bf(acc[i][j][rg] + bv);
      }
    }
  }
}

// ---------------- GATv2 aggregation: 1 wave/node, 4 edges in flight, per-head softmax ----
// 16 lanes/edge, 8 ch/lane; a head (32 ch) spans 4 aligned lanes -> reduce is xor 1,2 ONLY.
// Merge the 4 edge-slot states via xor 16,32. (8-edge variant regressed: deg~17 makes the
// 4-stage/16-ch merge dominate — measured r10.)
// Also zeroes gsum+gsq (64KB) in the first 16 blocks (safe: prior layer's gn_apply done).
__global__ __launch_bounds__(256) void gat_agg(
    const unsigned short* __restrict__ xlr, int stride,
    const int* __restrict__ csr, const int* __restrict__ offs,
    const float* __restrict__ att, const float* __restrict__ bias,
    unsigned short* __restrict__ out, float* __restrict__ gz, int N) {
  int zt = blockIdx.x * 256 + threadIdx.x;
  if (zt < 4096) *(float4*)(gz + zt * 4) = make_float4(0.f, 0.f, 0.f, 0.f);
  int wid = zt >> 6;
  if (wid >= N) return;
  int lane = threadIdx.x & 63;
  int q = lane >> 4, ql = lane & 15;   // edge slot, channel group (8 ch each)
  float4 aA = *(const float4*)&att[ql * 8];
  float4 aB = *(const float4*)&att[ql * 8 + 4];
  uint4 ur = *(const uint4*)(xlr + (size_t)wid * stride + 128 + ql * 8);
  float r0 = bflo(ur.x), r1 = bfhi(ur.x), r2 = bflo(ur.y), r3 = bfhi(ur.y);
  float r4 = bflo(ur.z), r5 = bfhi(ur.z), r6 = bflo(ur.w), r7 = bfhi(ur.w);
  float m = -1e30f, L = 0.f;
  float s0 = 0.f, s1 = 0.f, s2 = 0.f, s3 = 0.f, s4 = 0.f, s5 = 0.f, s6 = 0.f, s7 = 0.f;
  int js = offs[wid], je = offs[wid + 1];
  for (int j = js + q; j < je; j += 4) {
    int s = csr[j];
    uint4 u = *(const uint4*)(xlr + (size_t)s * stride + ql * 8);
    float x0 = bflo(u.x), x1 = bfhi(u.x), x2 = bflo(u.y), x3 = bfhi(u.y);
    float x4 = bflo(u.z), x5 = bfhi(u.z), x6 = bflo(u.w), x7 = bfhi(u.w);
    float v0 = fmaxf(r0 + x0, 0.2f * (r0 + x0));
    float v1 = fmaxf(r1 + x1, 0.2f * (r1 + x1));
    float v2 = fmaxf(r2 + x2, 0.2f * (r2 + x2));
    float v3 = fmaxf(r3 + x3, 0.2f * (r3 + x3));
    float v4 = fmaxf(r4 + x4, 0.2f * (r4 + x4));
    float v5 = fmaxf(r5 + x5, 0.2f * (r5 + x5));
    float v6 = fmaxf(r6 + x6, 0.2f * (r6 + x6));
    float v7 = fmaxf(r7 + x7, 0.2f * (r7 + x7));
    float p = aA.x * v0 + aA.y * v1 + aA.z * v2 + aA.w * v3 +
              aB.x * v4 + aB.y * v5 + aB.z * v6 + aB.w * v7;
    p += __shfl_xor(p, 1); p += __shfl_xor(p, 2);   // per-head reduce (4 lanes = 32 ch)
    float mn = fmaxf(m, p);
    float ea = __expf(p - mn);
    float es = __expf(m - mn);
    L = L * es + ea;
    s0 = s0 * es + ea * x0; s1 = s1 * es + ea * x1;
    s2 = s2 * es + ea * x2; s3 = s3 * es + ea * x3;
    s4 = s4 * es + ea * x4; s5 = s5 * es + ea * x5;
    s6 = s6 * es + ea * x6; s7 = s7 * es + ea * x7;
    m = mn;
  }
  // merge the 4 edge-slot states (per head/channel-slice)
#pragma unroll
  for (int d = 16; d <= 32; d <<= 1) {
    float mo = __shfl_xor(m, d), Lo = __shfl_xor(L, d);
    float t0 = __shfl_xor(s0, d), t1 = __shfl_xor(s1, d);
    float t2 = __shfl_xor(s2, d), t3 = __shfl_xor(s3, d);
    float t4 = __shfl_xor(s4, d), t5 = __shfl_xor(s5, d);
    float t6 = __shfl_xor(s6, d), t7 = __shfl_xor(s7, d);
    float mn = fmaxf(m, mo);
    float e0 = __expf(m - mn), e1 = __expf(mo - mn);
    L = L * e0 + Lo * e1;
    s0 = s0 * e0 + t0 * e1; s1 = s1 * e0 + t1 * e1;
    s2 = s2 * e0 + t2 * e1; s3 = s3 * e0 + t3 * e1;
    s4 = s4 * e0 + t4 * e1; s5 = s5 * e0 + t5 * e1;
    s6 = s6 * e0 + t6 * e1; s7 = s7 * e0 + t7 * e1;
    m = mn;
  }
  if (q == 0) {
    float inv = 1.f / L;
    float4 bA = *(const float4*)&bias[ql * 8];
    float4 bB = *(const float4*)&bias[ql * 8 + 4];
    uint4 ov;
    ov.x = bfpack(s0 * inv + bA.x, s1 * inv + bA.y);
    ov.y = bfpack(s2 * inv + bA.z, s3 * inv + bA.w);
    ov.z = bfpack(s4 * inv + bB.x, s5 * inv + bB.y);
    ov.w = bfpack(s6 * inv + bB.z, s7 * inv + bB.w);
    *(uint4*)(out + (size_t)wid * DD + ql * 8) = ov;
  }
}

// ---------------- GraphNorm stats (bf16 input, uint-vectorized) ----------------
__global__ __launch_bounds__(256) void gn_stats2(const unsigned short* __restrict__ x,
                                                 const int* __restrict__ bids,
                                                 float* __restrict__ gsum,
                                                 float* __restrict__ gsq, int N) {
  int base = blockIdx.x * 128;
  int cp = threadIdx.x & 63;   // channel pair
  int sub = threadIdx.x >> 6;  // row offset 0..3
  int end = base + 128 < N ? base + 128 : N;
  int curg = -1;
  float s0 = 0.f, s1 = 0.f, q0 = 0.f, q1 = 0.f;
  for (int r = base + sub; r < end; r += 4) {
    int g = bids[r];
    if (g != curg) {
      if (curg >= 0) {
        atomicAdd(&gsum[curg * DD + cp * 2], s0);
        atomicAdd(&gsum[curg * DD + cp * 2 + 1], s1);
        atomicAdd(&gsq[curg * DD + cp * 2], q0);
        atomicAdd(&gsq[curg * DD + cp * 2 + 1], q1);
      }
      curg = g; s0 = s1 = q0 = q1 = 0.f;
    }
    uint32_t u = *(const uint32_t*)(x + (size_t)r * DD + cp * 2);
    float v0 = bflo(u), v1 = bfhi(u);
    s0 += v0; q0 += v0 * v0; s1 += v1; q1 += v1 * v1;
  }
  if (curg >= 0) {
    atomicAdd(&gsum[curg * DD + cp * 2], s0);
    atomicAdd(&gsum[curg * DD + cp * 2 + 1], s1);
    atomicAdd(&gsq[curg * DD + cp * 2], q0);
    atomicAdd(&gsq[curg * DD + cp * 2 + 1], q1);
  }
}

// ---------------- GraphNorm apply + ELU (+residual) : bf16 in -> bf16 out --------------
template <bool ADDRES>
__global__ void gn_apply(const unsigned short* __restrict__ xin,
                         unsigned short* __restrict__ xout,
                         const unsigned short* __restrict__ res, int resStride,
                         const int* __restrict__ bids, const float* __restrict__ gsum,
                         const float* __restrict__ gsq, const float* __restrict__ invcnt,
                         const float* __restrict__ w, const float* __restrict__ b,
                         const float* __restrict__ ms, int N) {
  int idx = blockIdx.x * 256 + threadIdx.x;
  if (idx >= N * 64) return;
  int n = idx >> 6, cp = idx & 63;
  int g = bids[n];
  float ic = invcnt[g];
  float2 sm = *(const float2*)&gsum[g * DD + cp * 2];
  float2 sq = *(const float2*)&gsq[g * DD + cp * 2];
  float2 w2 = *(const float2*)&w[cp * 2];
  float2 b2 = *(const float2*)&b[cp * 2];
  float2 m2 = *(const float2*)&ms[cp * 2];
  uint32_t u = *(const uint32_t*)(xin + (size_t)n * DD + cp * 2);
  float mean0 = sm.x * ic, mean1 = sm.y * ic;
  float mm0 = mean0 * m2.x, mm1 = mean1 * m2.y;
  float var0 = sq.x * ic - mm0 * (2.f * mean0 - mm0);
  float var1 = sq.y * ic - mm1 * (2.f * mean1 - mm1);
  float v0 = (bflo(u) - mm0) * rsqrtf(var0 + 1e-5f) * w2.x + b2.x;
  float v1 = (bfhi(u) - mm1) * rsqrtf(var1 + 1e-5f) * w2.y + b2.y;
  if (ADDRES) {
    uint32_t ur = *(const uint32_t*)(res + (size_t)n * resStride + cp * 2);
    v0 += bflo(ur); v1 += bfhi(ur);
  }
  v0 = v0 > 0.f ? v0 : (__expf(v0) - 1.f);
  v1 = v1 > 0.f ? v1 : (__expf(v1) - 1.f);
  *(uint32_t*)(xout + (size_t)n * DD + cp * 2) = bfpack(v0, v1);
}

// ---------------- LSTM step: BK=64 staged (r12 structure), linear k-layout --------------
// r13 lesson: L2-direct MFMA regressed (scattered 64B segs, no latency decoupling) — keep
// LDS staging. k-permutation invariance (validated r13): stage rows LINEARLY (stride 144B,
// 16B-aligned, 2-way banking = free), single uint4 store per unit, fragment k = c*32+fg*8.
// Block: 256 thr (4 waves = 2 row x 2 col), 128 rows x 32 h-ch, 32.3KB LDS, 4 blocks/CU.
// (256,4): r11 showed tighter VGPR caps spill prefetch regs to scratch.
template <int KD>
__global__ __launch_bounds__(256, 4) void lstm_big(
    const unsigned short* __restrict__ A, const unsigned short* __restrict__ Bp,
    const float* __restrict__ bsum, unsigned short* __restrict__ H, int M) {
  __shared__ __attribute__((aligned(16))) char As_[128 * 144];
  __shared__ __attribute__((aligned(16))) char Ws_[96 * 144];
  const int NPH = KD / 64;
  int npanel = (M + 127) >> 7;
  int b = blockIdx.x;
  int g8 = b & 7, inner = b >> 3;
  int p = g8 + 8 * (inner >> 3);
  int cc = inner & 7;
  if (p >= npanel) return;
  int rowBase = p << 7;
  int ch0 = cc * 32;

  int tid = threadIdx.x;
  int lane = tid & 63;
  int wid = tid >> 6;
  int wr2 = wid >> 1;   // 0..1 row-group (64 rows)
  int wc2 = wid & 1;    // 0..1 col-group (16 ch -> 48 gate rows)
  int fr = lane & 15, fg = lane >> 4;

  // A staging: 4 16B units/thread (1024 units = 128 rows x 8)
  int aldst[4], agoff[4];
  bool aval[4];
#pragma unroll
  for (int q = 0; q < 4; ++q) {
    int e = q * 256 + tid;
    int r = e >> 3, u = e & 7;
    aldst[q] = r * 144 + u * 16;
    aval[q] = (rowBase + r) < M;
    agoff[q] = (rowBase + r) * KD + u * 8;
  }
  // W staging: 3 units/thread (768 units = 96 rows x 8)
  int wldst[3], wgoff[3];
#pragma unroll
  for (int q = 0; q < 3; ++q) {
    int e = q * 256 + tid;
    int wrow = e >> 3, u = e & 7;
    int half = wrow >= 48 ? 1 : 0;
    int r3 = wrow - 48 * half;
    int grp = r3 >> 4;
    int goff = (grp == 0) ? 0 : (grp == 1 ? 512 : 768);
    int grow = goff + ch0 + 16 * half + (r3 & 15);
    wldst[q] = wrow * 144 + u * 16;
    wgoff[q] = grow * KD + u * 8;
  }

  float4v acc[4][3];
#pragma unroll
  for (int i = 0; i < 4; ++i)
#pragma unroll
    for (int j = 0; j < 3; ++j) acc[i][j] = (float4v){0.f, 0.f, 0.f, 0.f};

  uint4 va[4], vw[3];
#pragma unroll
  for (int q = 0; q < 4; ++q) {
    va[q] = make_uint4(0u, 0u, 0u, 0u);
    if (aval[q]) va[q] = *(const uint4*)(A + agoff[q]);
  }
#pragma unroll
  for (int q = 0; q < 3; ++q) vw[q] = *(const uint4*)(Bp + wgoff[q]);

#pragma unroll
  for (int ph = 0; ph < NPH; ++ph) {
    if (ph) __syncthreads();
#pragma unroll
    for (int q = 0; q < 4; ++q) *(uint4*)(As_ + aldst[q]) = va[q];
#pragma unroll
    for (int q = 0; q < 3; ++q) *(uint4*)(Ws_ + wldst[q]) = vw[q];
    __syncthreads();
    if (ph + 1 < NPH) {
      int koff = (ph + 1) * 64;
#pragma unroll
      for (int q = 0; q < 4; ++q) {
        va[q] = make_uint4(0u, 0u, 0u, 0u);
        if (aval[q]) va[q] = *(const uint4*)(A + agoff[q] + koff);
      }
#pragma unroll
      for (int q = 0; q < 3; ++q) vw[q] = *(const uint4*)(Bp + wgoff[q] + koff);
    }
    __builtin_amdgcn_s_setprio(1);
#pragma unroll
    for (int c = 0; c < 2; ++c) {
      short8v af[4], bf[3];
#pragma unroll
      for (int i = 0; i < 4; ++i)
        af[i] = *(const short8v*)(As_ + (64 * wr2 + 16 * i + fr) * 144 + c * 64 + fg * 16);
#pragma unroll
      for (int j = 0; j < 3; ++j)
        bf[j] = *(const short8v*)(Ws_ + (48 * wc2 + 16 * j + fr) * 144 + c * 64 + fg * 16);
#pragma unroll
      for (int i = 0; i < 4; ++i)
#pragma unroll
        for (int j = 0; j < 3; ++j)
          acc[i][j] = __builtin_amdgcn_mfma_f32_16x16x32_bf16(af[i], bf[j], acc[i][j], 0, 0, 0);
    }
    __builtin_amdgcn_s_setprio(0);
  }
  // epilogue: lane owns channel ch for 16 rows; activations in registers
  int chL = 16 * wc2 + fr;
  int ch = ch0 + chL;
  float bi = bsum[ch], bg = bsum[512 + ch], bo = bsum[768 + ch];
  unsigned short hv[16];
#pragma unroll
  for (int i = 0; i < 4; ++i) {
#pragma unroll
    for (int rg = 0; rg < 4; ++rg) {
      float iv = acc[i][0][rg] + bi;
      float gv = acc[i][1][rg] + bg;
      float ov = acc[i][2][rg] + bo;
      float c = sigm_(iv) * tanh_(gv);
      hv[i * 4 + rg] = f2bf(sigm_(ov) * tanh_(c));
    }
  }
  __syncthreads();
  unsigned short* Hs = (unsigned short*)As_;  // [128][40] = 10240B
#pragma unroll
  for (int i = 0; i < 4; ++i) {
#pragma unroll
    for (int rg = 0; rg < 4; ++rg) {
      int row = 64 * wr2 + 16 * i + 4 * fg + rg;
      Hs[row * 40 + chL] = hv[i * 4 + rg];
    }
  }
  __syncthreads();
#pragma unroll
  for (int q = 0; q < 2; ++q) {
    int e = q * 256 + tid;
    int row = e >> 2, seg = e & 3;
    if (rowBase + row < M) {
      uint4 v = *(const uint4*)(Hs + row * 40 + seg * 8);
      *(uint4*)(H + (size_t)(rowBase + row) * LSTMH + ch0 + seg * 8) = v;
    }
  }
}

// ---------------- LayerNorm + mean pool: 1 wave per 8 rows, register pooling ----------
__global__ __launch_bounds__(256) void ln_pool2(
    const unsigned short* __restrict__ h2, const int* __restrict__ bids,
    const float* __restrict__ lnw, const float* __restrict__ lnb,
    const float* __restrict__ invcnt, float* __restrict__ pooled, int N) {
  int wave = (blockIdx.x * 256 + threadIdx.x) >> 6;
  int lane = threadIdx.x & 63;
  int r0 = wave * 8;
  if (r0 >= N) return;
  float4 w4 = *(const float4*)&lnw[lane * 4];
  float4 b4 = *(const float4*)&lnb[lane * 4];
  float p0 = 0.f, p1 = 0.f, p2 = 0.f, p3 = 0.f;
  int curg = bids[r0];
  int rend = r0 + 8 < N ? r0 + 8 : N;
  for (int r = r0; r < rend; ++r) {
    int g = bids[r];
    if (g != curg) {
      float ic = invcnt[curg];
      atomicAdd(&pooled[curg * LSTMH + lane * 4 + 0], p0 * ic);
      atomicAdd(&pooled[curg * LSTMH + lane * 4 + 1], p1 * ic);
      atomicAdd(&pooled[curg * LSTMH + lane * 4 + 2], p2 * ic);
      atomicAdd(&pooled[curg * LSTMH + lane * 4 + 3], p3 * ic);
      p0 = p1 = p2 = p3 = 0.f;
      curg = g;
    }
    uint2 u = *(const uint2*)(h2 + (size_t)r * LSTMH + lane * 4);
    float v0 = bflo(u.x), v1 = bfhi(u.x), v2 = bflo(u.y), v3 = bfhi(u.y);
    float s = v0 + v1 + v2 + v3;
    float q = v0 * v0 + v1 * v1 + v2 * v2 + v3 * v3;
#pragma unroll
    for (int d = 1; d < 64; d <<= 1) { s += __shfl_xor(s, d); q += __shfl_xor(q, d); }
    float mu = s * (1.f / 256.f);
    float var = q * (1.f / 256.f) - mu * mu;
    float rs = rsqrtf(var + 1e-5f);
    p0 += w4.x * (v0 - mu) * rs + b4.x;
    p1 += w4.y * (v1 - mu) * rs + b4.y;
    p2 += w4.z * (v2 - mu) * rs + b4.z;
    p3 += w4.w * (v3 - mu) * rs + b4.w;
  }
  float ic = invcnt[curg];
  atomicAdd(&pooled[curg * LSTMH + lane * 4 + 0], p0 * ic);
  atomicAdd(&pooled[curg * LSTMH + lane * 4 + 1], p1 * ic);
  atomicAdd(&pooled[curg * LSTMH + lane * 4 + 2], p2 * ic);
  atomicAdd(&pooled[curg * LSTMH + lane * 4 + 3], p3 * ic);
}

// ---------------- FC + log_softmax ----------------
__global__ __launch_bounds__(64) void fc_lsm(const float* __restrict__ pooled,
                                             const float* __restrict__ W,
                                             const float* __restrict__ b, float* __restrict__ out) {
  int g = blockIdx.x;
  int t = threadIdx.x;
  float l0 = 0.f, l1 = 0.f, l2 = 0.f, l3 = 0.f;
  for (int k = t; k < LSTMH; k += 64) {
    float p = pooled[g * LSTMH + k];
    l0 += p * W[k * 4 + 0];
    l1 += p * W[k * 4 + 1];
    l2 += p * W[k * 4 + 2];
    l3 += p * W[k * 4 + 3];
  }
#pragma unroll
  for (int d = 1; d < 64; d <<= 1) {
    l0 += __shfl_xor(l0, d); l1 += __shfl_xor(l1, d);
    l2 += __shfl_xor(l2, d); l3 += __shfl_xor(l3, d);
  }
  if (t == 0) {
    float z[4] = {l0 + b[0], l1 + b[1], l2 + b[2], l3 + b[3]};
    float mx = fmaxf(fmaxf(z[0], z[1]), fmaxf(z[2], z[3]));
    float sum = __expf(z[0] - mx) + __expf(z[1] - mx) + __expf(z[2] - mx) + __expf(z[3] - mx);
    float ls = logf(sum);
#pragma unroll
    for (int o = 0; o < 4; ++o) out[g * 4 + o] = z[o] - mx - ls;
  }
}

// ---------------- host launch ----------------
extern "C" void kernel_launch(void* const* d_in, const int* in_sizes, int n_in,
                              void* d_out, int out_size, void* d_ws, size_t ws_size,
                              hipStream_t stream) {
  const int* node_labels = (const int*)d_in[0];
  const int* node_types = (const int*)d_in[1];
  const float* node_feat = (const float*)d_in[2];
  const int* edge_index = (const int*)d_in[3];
  const int* batch_ids = (const int*)d_in[4];
  const float* emb_label = (const float*)d_in[5];
  const float* emb_type = (const float*)d_in[6];
  const float* W_in = (const float*)d_in[7];
  const float* b_in = (const float*)d_in[8];
  const float* g1_Wl = (const float*)d_in[9];
  const float* g1_bl = (const float*)d_in[10];
  const float* g1_Wr = (const float*)d_in[11];
  const float* g1_br = (const float*)d_in[12];
  const float* g1_att = (const float*)d_in[13];
  const float* g1_bias = (const float*)d_in[14];
  const float* gn1_w = (const float*)d_in[15];
  const float* gn1_b = (const float*)d_in[16];
  const float* gn1_ms = (const float*)d_in[17];
  const float* g2_Wl = (const float*)d_in[18];
  const float* g2_bl = (const float*)d_in[19];
  const float* g2_Wr = (const float*)d_in[20];
  const float* g2_br = (const float*)d_in[21];
  const float* g2_att = (const float*)d_in[22];
  const float* g2_bias = (const float*)d_in[23];
  const float* gn2_w = (const float*)d_in[24];
  const float* gn2_b = (const float*)d_in[25];
  const float* gn2_ms = (const float*)d_in[26];
  const float* W_res = (const float*)d_in[27];
  const float* b_res = (const float*)d_in[28];
  const float* l1_Wih = (const float*)d_in[29];
  const float* l1_bih = (const float*)d_in[31];
  const float* l1_bhh = (const float*)d_in[32];
  const float* l2_Wih = (const float*)d_in[33];
  const float* l2_bih = (const float*)d_in[35];
  const float* l2_bhh = (const float*)d_in[36];
  const float* ln_w = (const float*)d_in[37];
  const float* ln_b = (const float*)d_in[38];
  const float* fc_W = (const float*)d_in[39];
  const float* fc_b = (const float*)d_in[40];
  float* out = (float*)d_out;

  const int N = in_sizes[0];
  const int E = in_sizes[3] / 2;
  const int G = out_size / 4;
  const int ET = E + N;

  char* wsb = (char*)d_ws;
  size_t off = 0;
  auto alloc = [&](size_t bytes) -> void* {
    void* p = (void*)(wsb + off);
    off = (off + bytes + 255) & ~(size_t)255;
    return p;
  };
  unsigned short* xA = (unsigned short*)alloc((size_t)N * 512);       // gat out bf16; later h2
  unsigned short* xb = (unsigned short*)alloc((size_t)N * DD * 2);    // bf16 x / x1 / x2
  unsigned short* xlr = (unsigned short*)alloc((size_t)N * 384 * 2);  // xl|xr(|res); later h1
  int* deg = (int*)alloc((size_t)N * 4);
  int* offs = (int*)alloc((size_t)(N + 1) * 4);
  int* cursor = (int*)alloc((size_t)N * 4);
  int* partials = (int*)alloc(1024);
  int* csr = (int*)alloc((size_t)ET * 4);
  int* gstart = (int*)alloc((size_t)(G + 1) * 4);
  float* invcnt = (float*)alloc((size_t)G * 4);
  float* gsum = (float*)alloc((size_t)G * DD * 4);   // contiguous with gsq (32KB each)
  float* gsq = (float*)alloc((size_t)G * DD * 4);
  float* pooled = (float*)alloc((size_t)G * LSTMH * 4);
  float* bcat1 = (float*)alloc(256 * 4);
  float* bcat2 = (float*)alloc(384 * 4);
  float* bsum1 = (float*)alloc(ZG * 4);
  float* bsum2 = (float*)alloc(ZG * 4);
  unsigned short* wcat1 = (unsigned short*)alloc((size_t)256 * DD * 2);
  unsigned short* wcat2 = (unsigned short*)alloc((size_t)384 * DD * 2);
  unsigned short* wl1b = (unsigned short*)alloc((size_t)ZG * DD * 2);
  unsigned short* wl2b = (unsigned short*)alloc((size_t)ZG * LSTMH * 2);
  (void)ws_size; (void)n_in;

  unsigned short* h1 = xlr;   // [N][256] bf16, written after xlr dead
  unsigned short* h2 = xA;    // [N][256] bf16, written after xA dead

  int prepTotal = 477824 + 2 * N + 16384;
  prep_all<<<cdiv_(prepTotal, 256), 256, 0, stream>>>(
      g1_Wl, g1_Wr, g2_Wl, g2_Wr, W_res, l1_Wih, l2_Wih,
      g1_bl, g1_br, g2_bl, g2_br, b_res, l1_bih, l1_bhh, l2_bih, l2_bhh,
      wcat1, wcat2, wl1b, wl2b, bcat1, bcat2, bsum1, bsum2,
      deg, cursor, pooled, N);
  graph_ranges<<<1, 128, 0, stream>>>(batch_ids, gstart, invcnt, N, G);
  embed_in2<<<cdiv_(N, 128), 256, 0, stream>>>(node_labels, node_types, node_feat, emb_label,
                                               emb_type, W_in, b_in, xb, N);

  // CSR by dst
  count_deg<<<cdiv_(ET, 256), 256, 0, stream>>>(edge_index, deg, E, N);
  int nb1 = cdiv_(N, 256);
  scan1<<<nb1, 256, 0, stream>>>(deg, offs, partials, N);
  scan2<<<1, 256, 0, stream>>>(partials, offs, nb1, N);
  scan3<<<nb1, 256, 0, stream>>>(offs, partials, N);
  fill_csr<<<cdiv_(ET, 256), 256, 0, stream>>>(edge_index, offs, cursor, csr, E, N);

  int mb = cdiv_(N, 128);
  // ---- GAT layer 1: [xl|xr] in one GEMM ----
  gemm_bf16<<<dim3(2, mb), 256, 0, stream>>>(xb, wcat1, bcat1, xlr, N, DD, 256);
  gat_agg<<<cdiv_(N, 4), 256, 0, stream>>>(xlr, 256, csr, offs, g1_att, g1_bias, xA, gsum, N);
  gn_stats2<<<cdiv_(N, 128), 256, 0, stream>>>(xA, batch_ids, gsum, gsq, N);
  gn_apply<false><<<cdiv_(N * 64, 256), 256, 0, stream>>>(
      xA, xb, nullptr, 0, batch_ids, gsum, gsq, invcnt, gn1_w, gn1_b, gn1_ms, N);
  // ---- GAT layer 2: [xl|xr|res] in one GEMM ----
  gemm_bf16<<<dim3(3, mb), 256, 0, stream>>>(xb, wcat2, bcat2, xlr, N, DD, 384);
  gat_agg<<<cdiv_(N, 4), 256, 0, stream>>>(xlr, 384, csr, offs, g2_att, g2_bias, xA, gsum, N);
  gn_stats2<<<cdiv_(N, 128), 256, 0, stream>>>(xA, batch_ids, gsum, gsq, N);
  gn_apply<true><<<cdiv_(N * 64, 256), 256, 0, stream>>>(
      xA, xb, xlr + 256, 384, batch_ids, gsum, gsq, invcnt, gn2_w, gn2_b, gn2_ms, N);
  // ---- LSTM x2: BK=64 staged, linear k-layout, 4 blocks/CU, XCD-swizzled ----
  int npanel = cdiv_(N, 128);
  int lblocks = 64 * cdiv_(npanel, 8);
  lstm_big<DD><<<lblocks, 256, 0, stream>>>(xb, wl1b, bsum1, h1, N);
  lstm_big<LSTMH><<<lblocks, 256, 0, stream>>>(h1, wl2b, bsum2, h2, N);
  // ---- LN + mean pool + FC ----
  ln_pool2<<<cdiv_(N, 32), 256, 0, stream>>>(h2, batch_ids, ln_w, ln_b, invcnt, pooled, N);
  fc_lsm<<<G, 64, 0, stream>>>(pooled, fc_W, fc_b, out);
}

// Round 15
// 469.940 us; speedup vs baseline: 1.0973x; 1.0281x over previous
//
#include <hip/hip_runtime.h>
#include <cstdint>
#include <cstddef>

#define DD 128
#define LSTMH 256
#define ZG 1024

typedef __attribute__((ext_vector_type(8))) short short8v;
typedef __attribute__((ext_vector_type(4))) float float4v;

static inline int cdiv_(int a, int b) { return (a + b - 1) / b; }

__device__ __forceinline__ float sigm_(float x) { return 1.f / (1.f + __expf(-x)); }
__device__ __forceinline__ float tanh_(float x) {
  float e = __expf(-2.f * fabsf(x));
  float r = (1.f - e) / (1.f + e);
  return copysignf(r, x);
}

__device__ __forceinline__ unsigned short f2bf(float f) {
  uint32_t u = __float_as_uint(f);
  u += 0x7fffu + ((u >> 16) & 1u);
  return (unsigned short)(u >> 16);
}
__device__ __forceinline__ uint32_t bfpack(float a, float b) {
  return (uint32_t)f2bf(a) | ((uint32_t)f2bf(b) << 16);
}
__device__ __forceinline__ float bflo(uint32_t u) { return __uint_as_float(u << 16); }
__device__ __forceinline__ float bfhi(uint32_t u) { return __uint_as_float(u & 0xffff0000u); }

// ------- fused prep: 5 transposes + 2 casts + biases + deg/cursor/pooled zero, 1 launch --
__global__ void prep_all(const float* __restrict__ g1Wl, const float* __restrict__ g1Wr,
                         const float* __restrict__ g2Wl, const float* __restrict__ g2Wr,
                         const float* __restrict__ Wres, const float* __restrict__ l1Wih,
                         const float* __restrict__ l2Wih, const float* __restrict__ g1bl,
                         const float* __restrict__ g1br, const float* __restrict__ g2bl,
                         const float* __restrict__ g2br, const float* __restrict__ bres,
                         const float* __restrict__ l1bih, const float* __restrict__ l1bhh,
                         const float* __restrict__ l2bih, const float* __restrict__ l2bhh,
                         unsigned short* __restrict__ wcat1, unsigned short* __restrict__ wcat2,
                         unsigned short* __restrict__ wl1b, unsigned short* __restrict__ wl2b,
                         float* __restrict__ bcat1, float* __restrict__ bcat2,
                         float* __restrict__ bsum1, float* __restrict__ bsum2,
                         int* __restrict__ deg, int* __restrict__ cursor,
                         float* __restrict__ pooled, int Nn) {
  int i = blockIdx.x * 256 + threadIdx.x;
  if (i < 81920) {  // five 128x128 transposes -> [M][K] bf16
    int seg = i >> 14, j = i & 16383;
    int m = j >> 7, k = j & 127;
    const float* src = (seg == 0) ? g1Wl : (seg == 1) ? g1Wr : (seg == 2) ? g2Wl
                       : (seg == 3) ? g2Wr : Wres;
    unsigned short* dst = (seg == 0) ? wcat1 : (seg == 1) ? wcat1 + 16384
                          : (seg == 2) ? wcat2 : (seg == 3) ? wcat2 + 16384 : wcat2 + 32768;
    dst[j] = f2bf(src[k * 128 + m]);
    return;
  }
  i -= 81920;
  if (i < 131072) { wl1b[i] = f2bf(l1Wih[i]); return; }
  i -= 131072;
  if (i < 262144) { wl2b[i] = f2bf(l2Wih[i]); return; }
  i -= 262144;
  if (i < 256) { bcat1[i] = (i < 128) ? g1bl[i] : g1br[i - 128]; return; }
  i -= 256;
  if (i < 384) {
    bcat2[i] = (i < 128) ? g2bl[i] : (i < 256 ? g2br[i - 128] : bres[i - 256]);
    return;
  }
  i -= 384;
  if (i < 1024) { bsum1[i] = l1bih[i] + l1bhh[i]; return; }
  i -= 1024;
  if (i < 1024) { bsum2[i] = l2bih[i] + l2bhh[i]; return; }
  i -= 1024;
  if (i < Nn) { deg[i] = 0; return; }
  i -= Nn;
  if (i < Nn) { cursor[i] = 0; return; }
  i -= Nn;
  if (i < 16384) { pooled[i] = 0.f; return; }
}

// ---------------- embedding + W_in GEMV: 128 nodes/block, W in registers ----------------
__global__ __launch_bounds__(256) void embed_in2(
    const int* __restrict__ labels, const int* __restrict__ types,
    const float* __restrict__ nf, const float* __restrict__ embL,
    const float* __restrict__ embT, const float* __restrict__ W,
    const float* __restrict__ b, unsigned short* __restrict__ x, int N) {
  __shared__ float f[128][34];
  int base = blockIdx.x * 128;
  int tid = threadIdx.x;
  int ch = tid & 127, half = tid >> 7;
  float wr[33];
#pragma unroll
  for (int k = 0; k < 33; ++k) wr[k] = W[k * 128 + ch];
  float bb = b[ch];
  int nmax = N - base < 128 ? N - base : 128;
  for (int e = tid; e < nmax * 32; e += 256) {
    int n = e >> 5, k = e & 31;
    f[n][k] = (k < 16) ? embL[labels[base + n] * 16 + k] : embT[types[base + n] * 16 + (k - 16)];
  }
  for (int n = tid; n < nmax; n += 256) f[n][32] = nf[base + n];
  __syncthreads();
  for (int n = half; n < nmax; n += 2) {
    float acc = bb;
#pragma unroll
    for (int k = 0; k < 33; ++k) acc = fmaf(f[n][k], wr[k], acc);
    x[(size_t)(base + n) * 128 + ch] = f2bf(acc);
  }
}

// ---------------- CSR build ----------------
__global__ void count_deg(const int* __restrict__ ei, int* __restrict__ deg, int E_, int N_) {
  int i = blockIdx.x * 256 + threadIdx.x;
  if (i < E_) atomicAdd(&deg[ei[E_ + i]], 1);
  else if (i < E_ + N_) atomicAdd(&deg[i - E_], 1);
}

__global__ __launch_bounds__(256) void scan1(const int* __restrict__ deg, int* __restrict__ offs,
                                             int* __restrict__ partials, int N_) {
  __shared__ int buf[2][256];
  int tid = threadIdx.x;
  int i = blockIdx.x * 256 + tid;
  int v = (i < N_) ? deg[i] : 0;
  buf[0][tid] = v;
  __syncthreads();
  int cur = 0;
#pragma unroll
  for (int d = 1; d < 256; d <<= 1) {
    int xv = buf[cur][tid];
    if (tid >= d) xv += buf[cur][tid - d];
    buf[cur ^ 1][tid] = xv;
    cur ^= 1;
    __syncthreads();
  }
  int incl = buf[cur][tid];
  if (i < N_) offs[i] = incl - v;
  if (tid == 255) partials[blockIdx.x] = incl;
}

__global__ __launch_bounds__(256) void scan2(int* __restrict__ partials, int* __restrict__ offs,
                                             int nb, int N_) {
  __shared__ int buf[2][256];
  int tid = threadIdx.x;
  int v = (tid < nb) ? partials[tid] : 0;
  buf[0][tid] = v;
  __syncthreads();
  int cur = 0;
#pragma unroll
  for (int d = 1; d < 256; d <<= 1) {
    int xv = buf[cur][tid];
    if (tid >= d) xv += buf[cur][tid - d];
    buf[cur ^ 1][tid] = xv;
    cur ^= 1;
    __syncthreads();
  }
  int incl = buf[cur][tid];
  if (tid < nb) partials[tid] = incl - v;
  if (tid == 255) offs[N_] = incl;
}

__global__ void scan3(int* __restrict__ offs, const int* __restrict__ partials, int N_) {
  int i = blockIdx.x * 256 + threadIdx.x;
  if (i < N_) offs[i] += partials[blockIdx.x];
}

__global__ void fill_csr(const int* __restrict__ ei, const int* __restrict__ offs,
                         int* __restrict__ cursor, int* __restrict__ csr, int E_, int N_) {
  int i = blockIdx.x * 256 + threadIdx.x;
  int s, d;
  if (i < E_) { s = ei[i]; d = ei[E_ + i]; }
  else if (i < E_ + N_) { s = d = i - E_; }
  else return;
  int pos = offs[d] + atomicAdd(&cursor[d], 1);
  csr[pos] = s;
}

// ---------------- graph ranges ----------------
__global__ void graph_ranges(const int* __restrict__ bids, int* __restrict__ gstart,
                             float* __restrict__ invcnt, int N_, int G_) {
  int t = threadIdx.x;
  if (t <= G_) {
    int lo = 0, hi = N_;
    while (lo < hi) { int mid = (lo + hi) >> 1; if (bids[mid] < t) lo = mid + 1; else hi = mid; }
    gstart[t] = lo;
  }
  __syncthreads();
  if (t < G_) {
    int c = gstart[t + 1] - gstart[t];
    invcnt[t] = (c > 0) ? 1.f / (float)c : 0.f;
  }
}

// ---------------- bf16 MFMA GEMM: C[M,Ncols] bf16 = A[M,K]bf16 @ B'[Ncols,K]^T + bias
__global__ __launch_bounds__(256) void gemm_bf16(
    const unsigned short* __restrict__ A, const unsigned short* __restrict__ Bp,
    const float* __restrict__ bias, unsigned short* __restrict__ C, int M, int K, int Ncols) {
  __shared__ unsigned short As[128 * 40];
  __shared__ unsigned short Bs[128 * 40];
  int tid = threadIdx.x;
  int lane = tid & 63;
  int wid = tid >> 6;
  int rowBase = blockIdx.y * 128, colBase = blockIdx.x * 128;
  int wr = (wid >> 1) * 64, wc = (wid & 1) * 64;
  int fr = lane & 15, fg = lane >> 4;
  float4v acc[4][4];
#pragma unroll
  for (int i = 0; i < 4; ++i)
#pragma unroll
    for (int j = 0; j < 4; ++j) acc[i][j] = (float4v){0.f, 0.f, 0.f, 0.f};

  int sr = tid >> 2;
  int sc = tid & 3;
  int off_lo = (sc < 2) ? 32 * sc : 32 * sc - 56;

  for (int k0 = 0; k0 < K; k0 += 32) {
#pragma unroll
    for (int it = 0; it < 2; ++it) {
      int r = it * 64 + sr;
      uint4 va = make_uint4(0u, 0u, 0u, 0u);
      if (rowBase + r < M)
        va = *(const uint4*)(A + (size_t)(rowBase + r) * K + k0 + sc * 8);
      char* arow = (char*)(As + r * 40);
      *(uint2*)(arow + off_lo) = make_uint2(va.x, va.y);
      *(uint2*)(arow + off_lo + 16) = make_uint2(va.z, va.w);
      uint4 vb = *(const uint4*)(Bp + (size_t)(colBase + r) * K + k0 + sc * 8);
      char* brow = (char*)(Bs + r * 40);
      *(uint2*)(brow + off_lo) = make_uint2(vb.x, vb.y);
      *(uint2*)(brow + off_lo + 16) = make_uint2(vb.z, vb.w);
    }
    __syncthreads();
    short8v af[4], bfv[4];
#pragma unroll
    for (int i = 0; i < 4; ++i)
      af[i] = *(const short8v*)((const char*)As + (wr + 16 * i + fr) * 80 + fg * 16);
#pragma unroll
    for (int j = 0; j < 4; ++j)
      bfv[j] = *(const short8v*)((const char*)Bs + (wc + 16 * j + fr) * 80 + fg * 16);
#pragma unroll
    for (int i = 0; i < 4; ++i)
#pragma unroll
      for (int j = 0; j < 4; ++j)
        acc[i][j] = __builtin_amdgcn_mfma_f32_16x16x32_bf16(af[i], bfv[j], acc[i][j], 0, 0, 0);
    __syncthreads();
  }
#pragma unroll
  for (int j = 0; j < 4; ++j) {
    int gc = colBase + wc + 16 * j + fr;
    float bv = bias[gc];
#pragma unroll
    for (int i = 0; i < 4; ++i) {
      int gr0 = rowBase + wr + 16 * i + fg * 4;
#pragma unroll
      for (int rg = 0; rg < 4; ++rg) {
        int gr = gr0 + rg;
        if (gr < M) C[(size_t)gr * Ncols + gc] = f2bf(acc[i][j][rg] + bv);
      }
    }
  }
}

// ---------------- GATv2 aggregation: 1 wave/node, 4 edges in flight, per-head softmax ----
// 16 lanes/edge, 8 ch/lane; a head (32 ch) spans 4 aligned lanes -> reduce is xor 1,2 ONLY.
// Merge the 4 edge-slot states via xor 16,32. (8-edge variant regressed: deg~17 makes the
// 4-stage/16-ch merge dominate — measured r10.)
// Also zeroes gsum+gsq (64KB) in the first 16 blocks (safe: prior layer's gn_apply done).
__global__ __launch_bounds__(256) void gat_agg(
    const unsigned short* __restrict__ xlr, int stride,
    const int* __restrict__ csr, const int* __restrict__ offs,
    const float* __restrict__ att, const float* __restrict__ bias,
    unsigned short* __restrict__ out, float* __restrict__ gz, int N) {
  int zt = blockIdx.x * 256 + threadIdx.x;
  if (zt < 4096) *(float4*)(gz + zt * 4) = make_float4(0.f, 0.f, 0.f, 0.f);
  int wid = zt >> 6;
  if (wid >= N) return;
  int lane = threadIdx.x & 63;
  int q = lane >> 4, ql = lane & 15;   // edge slot, channel group (8 ch each)
  float4 aA = *(const float4*)&att[ql * 8];
  float4 aB = *(const float4*)&att[ql * 8 + 4];
  uint4 ur = *(const uint4*)(xlr + (size_t)wid * stride + 128 + ql * 8);
  float r0 = bflo(ur.x), r1 = bfhi(ur.x), r2 = bflo(ur.y), r3 = bfhi(ur.y);
  float r4 = bflo(ur.z), r5 = bfhi(ur.z), r6 = bflo(ur.w), r7 = bfhi(ur.w);
  float m = -1e30f, L = 0.f;
  float s0 = 0.f, s1 = 0.f, s2 = 0.f, s3 = 0.f, s4 = 0.f, s5 = 0.f, s6 = 0.f, s7 = 0.f;
  int js = offs[wid], je = offs[wid + 1];
  for (int j = js + q; j < je; j += 4) {
    int s = csr[j];
    uint4 u = *(const uint4*)(xlr + (size_t)s * stride + ql * 8);
    float x0 = bflo(u.x), x1 = bfhi(u.x), x2 = bflo(u.y), x3 = bfhi(u.y);
    float x4 = bflo(u.z), x5 = bfhi(u.z), x6 = bflo(u.w), x7 = bfhi(u.w);
    float v0 = fmaxf(r0 + x0, 0.2f * (r0 + x0));
    float v1 = fmaxf(r1 + x1, 0.2f * (r1 + x1));
    float v2 = fmaxf(r2 + x2, 0.2f * (r2 + x2));
    float v3 = fmaxf(r3 + x3, 0.2f * (r3 + x3));
    float v4 = fmaxf(r4 + x4, 0.2f * (r4 + x4));
    float v5 = fmaxf(r5 + x5, 0.2f * (r5 + x5));
    float v6 = fmaxf(r6 + x6, 0.2f * (r6 + x6));
    float v7 = fmaxf(r7 + x7, 0.2f * (r7 + x7));
    float p = aA.x * v0 + aA.y * v1 + aA.z * v2 + aA.w * v3 +
              aB.x * v4 + aB.y * v5 + aB.z * v6 + aB.w * v7;
    p += __shfl_xor(p, 1); p += __shfl_xor(p, 2);   // per-head reduce (4 lanes = 32 ch)
    float mn = fmaxf(m, p);
    float ea = __expf(p - mn);
    float es = __expf(m - mn);
    L = L * es + ea;
    s0 = s0 * es + ea * x0; s1 = s1 * es + ea * x1;
    s2 = s2 * es + ea * x2; s3 = s3 * es + ea * x3;
    s4 = s4 * es + ea * x4; s5 = s5 * es + ea * x5;
    s6 = s6 * es + ea * x6; s7 = s7 * es + ea * x7;
    m = mn;
  }
  // merge the 4 edge-slot states (per head/channel-slice)
#pragma unroll
  for (int d = 16; d <= 32; d <<= 1) {
    float mo = __shfl_xor(m, d), Lo = __shfl_xor(L, d);
    float t0 = __shfl_xor(s0, d), t1 = __shfl_xor(s1, d);
    float t2 = __shfl_xor(s2, d), t3 = __shfl_xor(s3, d);
    float t4 = __shfl_xor(s4, d), t5 = __shfl_xor(s5, d);
    float t6 = __shfl_xor(s6, d), t7 = __shfl_xor(s7, d);
    float mn = fmaxf(m, mo);
    float e0 = __expf(m - mn), e1 = __expf(mo - mn);
    L = L * e0 + Lo * e1;
    s0 = s0 * e0 + t0 * e1; s1 = s1 * e0 + t1 * e1;
    s2 = s2 * e0 + t2 * e1; s3 = s3 * e0 + t3 * e1;
    s4 = s4 * e0 + t4 * e1; s5 = s5 * e0 + t5 * e1;
    s6 = s6 * e0 + t6 * e1; s7 = s7 * e0 + t7 * e1;
    m = mn;
  }
  if (q == 0) {
    float inv = 1.f / L;
    float4 bA = *(const float4*)&bias[ql * 8];
    float4 bB = *(const float4*)&bias[ql * 8 + 4];
    uint4 ov;
    ov.x = bfpack(s0 * inv + bA.x, s1 * inv + bA.y);
    ov.y = bfpack(s2 * inv + bA.z, s3 * inv + bA.w);
    ov.z = bfpack(s4 * inv + bB.x, s5 * inv + bB.y);
    ov.w = bfpack(s6 * inv + bB.z, s7 * inv + bB.w);
    *(uint4*)(out + (size_t)wid * DD + ql * 8) = ov;
  }
}

// ---------------- GraphNorm stats (bf16 input, uint-vectorized) ----------------
__global__ __launch_bounds__(256) void gn_stats2(const unsigned short* __restrict__ x,
                                                 const int* __restrict__ bids,
                                                 float* __restrict__ gsum,
                                                 float* __restrict__ gsq, int N) {
  int base = blockIdx.x * 128;
  int cp = threadIdx.x & 63;   // channel pair
  int sub = threadIdx.x >> 6;  // row offset 0..3
  int end = base + 128 < N ? base + 128 : N;
  int curg = -1;
  float s0 = 0.f, s1 = 0.f, q0 = 0.f, q1 = 0.f;
  for (int r = base + sub; r < end; r += 4) {
    int g = bids[r];
    if (g != curg) {
      if (curg >= 0) {
        atomicAdd(&gsum[curg * DD + cp * 2], s0);
        atomicAdd(&gsum[curg * DD + cp * 2 + 1], s1);
        atomicAdd(&gsq[curg * DD + cp * 2], q0);
        atomicAdd(&gsq[curg * DD + cp * 2 + 1], q1);
      }
      curg = g; s0 = s1 = q0 = q1 = 0.f;
    }
    uint32_t u = *(const uint32_t*)(x + (size_t)r * DD + cp * 2);
    float v0 = bflo(u), v1 = bfhi(u);
    s0 += v0; q0 += v0 * v0; s1 += v1; q1 += v1 * v1;
  }
  if (curg >= 0) {
    atomicAdd(&gsum[curg * DD + cp * 2], s0);
    atomicAdd(&gsum[curg * DD + cp * 2 + 1], s1);
    atomicAdd(&gsq[curg * DD + cp * 2], q0);
    atomicAdd(&gsq[curg * DD + cp * 2 + 1], q1);
  }
}

// ---------------- GraphNorm apply + ELU (+residual) : bf16 in -> bf16 out --------------
template <bool ADDRES>
__global__ void gn_apply(const unsigned short* __restrict__ xin,
                         unsigned short* __restrict__ xout,
                         const unsigned short* __restrict__ res, int resStride,
                         const int* __restrict__ bids, const float* __restrict__ gsum,
                         const float* __restrict__ gsq, const float* __restrict__ invcnt,
                         const float* __restrict__ w, const float* __restrict__ b,
                         const float* __restrict__ ms, int N) {
  int idx = blockIdx.x * 256 + threadIdx.x;
  if (idx >= N * 64) return;
  int n = idx >> 6, cp = idx & 63;
  int g = bids[n];
  float ic = invcnt[g];
  float2 sm = *(const float2*)&gsum[g * DD + cp * 2];
  float2 sq = *(const float2*)&gsq[g * DD + cp * 2];
  float2 w2 = *(const float2*)&w[cp * 2];
  float2 b2 = *(const float2*)&b[cp * 2];
  float2 m2 = *(const float2*)&ms[cp * 2];
  uint32_t u = *(const uint32_t*)(xin + (size_t)n * DD + cp * 2);
  float mean0 = sm.x * ic, mean1 = sm.y * ic;
  float mm0 = mean0 * m2.x, mm1 = mean1 * m2.y;
  float var0 = sq.x * ic - mm0 * (2.f * mean0 - mm0);
  float var1 = sq.y * ic - mm1 * (2.f * mean1 - mm1);
  float v0 = (bflo(u) - mm0) * rsqrtf(var0 + 1e-5f) * w2.x + b2.x;
  float v1 = (bfhi(u) - mm1) * rsqrtf(var1 + 1e-5f) * w2.y + b2.y;
  if (ADDRES) {
    uint32_t ur = *(const uint32_t*)(res + (size_t)n * resStride + cp * 2);
    v0 += bflo(ur); v1 += bfhi(ur);
  }
  v0 = v0 > 0.f ? v0 : (__expf(v0) - 1.f);
  v1 = v1 > 0.f ? v1 : (__expf(v1) - 1.f);
  *(uint32_t*)(xout + (size_t)n * DD + cp * 2) = bfpack(v0, v1);
}

// ---------------- LSTM step: BK=64, 256 thr (4 waves, 64 rows/wave), reg-prefetch --------
// Block: 128 rows x 32 h-channels (96 gate rows i|g|o), 30.7KB LDS, 4 blocks/CU.
// Best measured config (r12: 62us, FETCH 14MB, WRITE 25MB, no spill). Do NOT perturb:
// (256,5) spilled (r11: WRITE 141MB); L2-direct MFMA latency-bound (r13: 106us);
// linear-k single-store layout spilled (r14: WRITE 84MB).
template <int KD>
__global__ __launch_bounds__(256, 4) void lstm_big(
    const unsigned short* __restrict__ A, const unsigned short* __restrict__ Bp,
    const float* __restrict__ bsum, unsigned short* __restrict__ H, int M) {
  __shared__ __attribute__((aligned(16))) char As_[128 * 136];
  __shared__ __attribute__((aligned(16))) char Ws_[96 * 136];
  const int NPH = KD / 64;
  int npanel = (M + 127) >> 7;
  int b = blockIdx.x;
  int g8 = b & 7, inner = b >> 3;
  int p = g8 + 8 * (inner >> 3);
  int cc = inner & 7;
  if (p >= npanel) return;
  int rowBase = p << 7;
  int ch0 = cc * 32;

  int tid = threadIdx.x;
  int lane = tid & 63;
  int wid = tid >> 6;
  int wr2 = wid >> 1;   // 0..1 row-group (64 rows)
  int wc2 = wid & 1;    // 0..1 col-group (16 ch -> 48 gate rows)
  int fr = lane & 15, fg = lane >> 4;

  // A staging: 4 16B units/thread (1024 units = 128 rows x 8)
  int aldst[4], agoff[4];
  bool aval[4];
#pragma unroll
  for (int q = 0; q < 4; ++q) {
    int e = q * 256 + tid;
    int r = e >> 3, kk = e & 7;
    int c = kk >> 2, sc = kk & 3;
    int olo = (sc < 2) ? 32 * sc : 32 * sc - 56;
    aldst[q] = r * 136 + c * 64 + olo;
    aval[q] = (rowBase + r) < M;
    agoff[q] = (rowBase + r) * KD + c * 32 + sc * 8;
  }
  // W staging: 3 units/thread (768 units = 96 rows x 8)
  int wldst[3], wgoff[3];
#pragma unroll
  for (int q = 0; q < 3; ++q) {
    int e = q * 256 + tid;
    int wrow = e >> 3, kk = e & 7;
    int c = kk >> 2, sc = kk & 3;
    int half = wrow >= 48 ? 1 : 0;
    int r3 = wrow - 48 * half;
    int grp = r3 >> 4;
    int goff = (grp == 0) ? 0 : (grp == 1 ? 512 : 768);
    int grow = goff + ch0 + 16 * half + (r3 & 15);
    int olo = (sc < 2) ? 32 * sc : 32 * sc - 56;
    wldst[q] = wrow * 136 + c * 64 + olo;
    wgoff[q] = grow * KD + c * 32 + sc * 8;
  }

  float4v acc[4][3];
#pragma unroll
  for (int i = 0; i < 4; ++i)
#pragma unroll
    for (int j = 0; j < 3; ++j) acc[i][j] = (float4v){0.f, 0.f, 0.f, 0.f};

  uint4 va[4], vw[3];
#pragma unroll
  for (int q = 0; q < 4; ++q) {
    va[q] = make_uint4(0u, 0u, 0u, 0u);
    if (aval[q]) va[q] = *(const uint4*)(A + agoff[q]);
  }
#pragma unroll
  for (int q = 0; q < 3; ++q) vw[q] = *(const uint4*)(Bp + wgoff[q]);

#pragma unroll
  for (int ph = 0; ph < NPH; ++ph) {
    if (ph) __syncthreads();
#pragma unroll
    for (int q = 0; q < 4; ++q) {
      char* dst = As_ + aldst[q];
      *(uint2*)(dst) = make_uint2(va[q].x, va[q].y);
      *(uint2*)(dst + 16) = make_uint2(va[q].z, va[q].w);
    }
#pragma unroll
    for (int q = 0; q < 3; ++q) {
      char* dst = Ws_ + wldst[q];
      *(uint2*)(dst) = make_uint2(vw[q].x, vw[q].y);
      *(uint2*)(dst + 16) = make_uint2(vw[q].z, vw[q].w);
    }
    __syncthreads();
    if (ph + 1 < NPH) {
      int koff = (ph + 1) * 64;
#pragma unroll
      for (int q = 0; q < 4; ++q) {
        va[q] = make_uint4(0u, 0u, 0u, 0u);
        if (aval[q]) va[q] = *(const uint4*)(A + agoff[q] + koff);
      }
#pragma unroll
      for (int q = 0; q < 3; ++q) vw[q] = *(const uint4*)(Bp + wgoff[q] + koff);
    }
    __builtin_amdgcn_s_setprio(1);
#pragma unroll
    for (int c = 0; c < 2; ++c) {
      short8v af[4], bf[3];
#pragma unroll
      for (int i = 0; i < 4; ++i)
        af[i] = *(const short8v*)(As_ + (64 * wr2 + 16 * i + fr) * 136 + c * 64 + fg * 16);
#pragma unroll
      for (int j = 0; j < 3; ++j)
        bf[j] = *(const short8v*)(Ws_ + (48 * wc2 + 16 * j + fr) * 136 + c * 64 + fg * 16);
#pragma unroll
      for (int i = 0; i < 4; ++i)
#pragma unroll
        for (int j = 0; j < 3; ++j)
          acc[i][j] = __builtin_amdgcn_mfma_f32_16x16x32_bf16(af[i], bf[j], acc[i][j], 0, 0, 0);
    }
    __builtin_amdgcn_s_setprio(0);
  }
  // epilogue: lane owns channel ch for 16 rows; activations in registers
  int chL = 16 * wc2 + fr;
  int ch = ch0 + chL;
  float bi = bsum[ch], bg = bsum[512 + ch], bo = bsum[768 + ch];
  unsigned short hv[16];
#pragma unroll
  for (int i = 0; i < 4; ++i) {
#pragma unroll
    for (int rg = 0; rg < 4; ++rg) {
      float iv = acc[i][0][rg] + bi;
      float gv = acc[i][1][rg] + bg;
      float ov = acc[i][2][rg] + bo;
      float c = sigm_(iv) * tanh_(gv);
      hv[i * 4 + rg] = f2bf(sigm_(ov) * tanh_(c));
    }
  }
  __syncthreads();
  unsigned short* Hs = (unsigned short*)As_;  // [128][40] = 10240B
#pragma unroll
  for (int i = 0; i < 4; ++i) {
#pragma unroll
    for (int rg = 0; rg < 4; ++rg) {
      int row = 64 * wr2 + 16 * i + 4 * fg + rg;
      Hs[row * 40 + chL] = hv[i * 4 + rg];
    }
  }
  __syncthreads();
#pragma unroll
  for (int q = 0; q < 2; ++q) {
    int e = q * 256 + tid;
    int row = e >> 2, seg = e & 3;
    if (rowBase + row < M) {
      uint4 v = *(const uint4*)(Hs + row * 40 + seg * 8);
      *(uint4*)(H + (size_t)(rowBase + row) * LSTMH + ch0 + seg * 8) = v;
    }
  }
}

// ---------------- LayerNorm + mean pool: 1 wave per 8 rows, register pooling ----------
__global__ __launch_bounds__(256) void ln_pool2(
    const unsigned short* __restrict__ h2, const int* __restrict__ bids,
    const float* __restrict__ lnw, const float* __restrict__ lnb,
    const float* __restrict__ invcnt, float* __restrict__ pooled, int N) {
  int wave = (blockIdx.x * 256 + threadIdx.x) >> 6;
  int lane = threadIdx.x & 63;
  int r0 = wave * 8;
  if (r0 >= N) return;
  float4 w4 = *(const float4*)&lnw[lane * 4];
  float4 b4 = *(const float4*)&lnb[lane * 4];
  float p0 = 0.f, p1 = 0.f, p2 = 0.f, p3 = 0.f;
  int curg = bids[r0];
  int rend = r0 + 8 < N ? r0 + 8 : N;
  for (int r = r0; r < rend; ++r) {
    int g = bids[r];
    if (g != curg) {
      float ic = invcnt[curg];
      atomicAdd(&pooled[curg * LSTMH + lane * 4 + 0], p0 * ic);
      atomicAdd(&pooled[curg * LSTMH + lane * 4 + 1], p1 * ic);
      atomicAdd(&pooled[curg * LSTMH + lane * 4 + 2], p2 * ic);
      atomicAdd(&pooled[curg * LSTMH + lane * 4 + 3], p3 * ic);
      p0 = p1 = p2 = p3 = 0.f;
      curg = g;
    }
    uint2 u = *(const uint2*)(h2 + (size_t)r * LSTMH + lane * 4);
    float v0 = bflo(u.x), v1 = bfhi(u.x), v2 = bflo(u.y), v3 = bfhi(u.y);
    float s = v0 + v1 + v2 + v3;
    float q = v0 * v0 + v1 * v1 + v2 * v2 + v3 * v3;
#pragma unroll
    for (int d = 1; d < 64; d <<= 1) { s += __shfl_xor(s, d); q += __shfl_xor(q, d); }
    float mu = s * (1.f / 256.f);
    float var = q * (1.f / 256.f) - mu * mu;
    float rs = rsqrtf(var + 1e-5f);
    p0 += w4.x * (v0 - mu) * rs + b4.x;
    p1 += w4.y * (v1 - mu) * rs + b4.y;
    p2 += w4.z * (v2 - mu) * rs + b4.z;
    p3 += w4.w * (v3 - mu) * rs + b4.w;
  }
  float ic = invcnt[curg];
  atomicAdd(&pooled[curg * LSTMH + lane * 4 + 0], p0 * ic);
  atomicAdd(&pooled[curg * LSTMH + lane * 4 + 1], p1 * ic);
  atomicAdd(&pooled[curg * LSTMH + lane * 4 + 2], p2 * ic);
  atomicAdd(&pooled[curg * LSTMH + lane * 4 + 3], p3 * ic);
}

// ---------------- FC + log_softmax ----------------
__global__ __launch_bounds__(64) void fc_lsm(const float* __restrict__ pooled,
                                             const float* __restrict__ W,
                                             const float* __restrict__ b, float* __restrict__ out) {
  int g = blockIdx.x;
  int t = threadIdx.x;
  float l0 = 0.f, l1 = 0.f, l2 = 0.f, l3 = 0.f;
  for (int k = t; k < LSTMH; k += 64) {
    float p = pooled[g * LSTMH + k];
    l0 += p * W[k * 4 + 0];
    l1 += p * W[k * 4 + 1];
    l2 += p * W[k * 4 + 2];
    l3 += p * W[k * 4 + 3];
  }
#pragma unroll
  for (int d = 1; d < 64; d <<= 1) {
    l0 += __shfl_xor(l0, d); l1 += __shfl_xor(l1, d);
    l2 += __shfl_xor(l2, d); l3 += __shfl_xor(l3, d);
  }
  if (t == 0) {
    float z[4] = {l0 + b[0], l1 + b[1], l2 + b[2], l3 + b[3]};
    float mx = fmaxf(fmaxf(z[0], z[1]), fmaxf(z[2], z[3]));
    float sum = __expf(z[0] - mx) + __expf(z[1] - mx) + __expf(z[2] - mx) + __expf(z[3] - mx);
    float ls = logf(sum);
#pragma unroll
    for (int o = 0; o < 4; ++o) out[g * 4 + o] = z[o] - mx - ls;
  }
}

// ---------------- host launch ----------------
extern "C" void kernel_launch(void* const* d_in, const int* in_sizes, int n_in,
                              void* d_out, int out_size, void* d_ws, size_t ws_size,
                              hipStream_t stream) {
  const int* node_labels = (const int*)d_in[0];
  const int* node_types = (const int*)d_in[1];
  const float* node_feat = (const float*)d_in[2];
  const int* edge_index = (const int*)d_in[3];
  const int* batch_ids = (const int*)d_in[4];
  const float* emb_label = (const float*)d_in[5];
  const float* emb_type = (const float*)d_in[6];
  const float* W_in = (const float*)d_in[7];
  const float* b_in = (const float*)d_in[8];
  const float* g1_Wl = (const float*)d_in[9];
  const float* g1_bl = (const float*)d_in[10];
  const float* g1_Wr = (const float*)d_in[11];
  const float* g1_br = (const float*)d_in[12];
  const float* g1_att = (const float*)d_in[13];
  const float* g1_bias = (const float*)d_in[14];
  const float* gn1_w = (const float*)d_in[15];
  const float* gn1_b = (const float*)d_in[16];
  const float* gn1_ms = (const float*)d_in[17];
  const float* g2_Wl = (const float*)d_in[18];
  const float* g2_bl = (const float*)d_in[19];
  const float* g2_Wr = (const float*)d_in[20];
  const float* g2_br = (const float*)d_in[21];
  const float* g2_att = (const float*)d_in[22];
  const float* g2_bias = (const float*)d_in[23];
  const float* gn2_w = (const float*)d_in[24];
  const float* gn2_b = (const float*)d_in[25];
  const float* gn2_ms = (const float*)d_in[26];
  const float* W_res = (const float*)d_in[27];
  const float* b_res = (const float*)d_in[28];
  const float* l1_Wih = (const float*)d_in[29];
  const float* l1_bih = (const float*)d_in[31];
  const float* l1_bhh = (const float*)d_in[32];
  const float* l2_Wih = (const float*)d_in[33];
  const float* l2_bih = (const float*)d_in[35];
  const float* l2_bhh = (const float*)d_in[36];
  const float* ln_w = (const float*)d_in[37];
  const float* ln_b = (const float*)d_in[38];
  const float* fc_W = (const float*)d_in[39];
  const float* fc_b = (const float*)d_in[40];
  float* out = (float*)d_out;

  const int N = in_sizes[0];
  const int E = in_sizes[3] / 2;
  const int G = out_size / 4;
  const int ET = E + N;

  char* wsb = (char*)d_ws;
  size_t off = 0;
  auto alloc = [&](size_t bytes) -> void* {
    void* p = (void*)(wsb + off);
    off = (off + bytes + 255) & ~(size_t)255;
    return p;
  };
  unsigned short* xA = (unsigned short*)alloc((size_t)N * 512);       // gat out bf16; later h2
  unsigned short* xb = (unsigned short*)alloc((size_t)N * DD * 2);    // bf16 x / x1 / x2
  unsigned short* xlr = (unsigned short*)alloc((size_t)N * 384 * 2);  // xl|xr(|res); later h1
  int* deg = (int*)alloc((size_t)N * 4);
  int* offs = (int*)alloc((size_t)(N + 1) * 4);
  int* cursor = (int*)alloc((size_t)N * 4);
  int* partials = (int*)alloc(1024);
  int* csr = (int*)alloc((size_t)ET * 4);
  int* gstart = (int*)alloc((size_t)(G + 1) * 4);
  float* invcnt = (float*)alloc((size_t)G * 4);
  float* gsum = (float*)alloc((size_t)G * DD * 4);   // contiguous with gsq (32KB each)
  float* gsq = (float*)alloc((size_t)G * DD * 4);
  float* pooled = (float*)alloc((size_t)G * LSTMH * 4);
  float* bcat1 = (float*)alloc(256 * 4);
  float* bcat2 = (float*)alloc(384 * 4);
  float* bsum1 = (float*)alloc(ZG * 4);
  float* bsum2 = (float*)alloc(ZG * 4);
  unsigned short* wcat1 = (unsigned short*)alloc((size_t)256 * DD * 2);
  unsigned short* wcat2 = (unsigned short*)alloc((size_t)384 * DD * 2);
  unsigned short* wl1b = (unsigned short*)alloc((size_t)ZG * DD * 2);
  unsigned short* wl2b = (unsigned short*)alloc((size_t)ZG * LSTMH * 2);
  (void)ws_size; (void)n_in;

  unsigned short* h1 = xlr;   // [N][256] bf16, written after xlr dead
  unsigned short* h2 = xA;    // [N][256] bf16, written after xA dead

  int prepTotal = 477824 + 2 * N + 16384;
  prep_all<<<cdiv_(prepTotal, 256), 256, 0, stream>>>(
      g1_Wl, g1_Wr, g2_Wl, g2_Wr, W_res, l1_Wih, l2_Wih,
      g1_bl, g1_br, g2_bl, g2_br, b_res, l1_bih, l1_bhh, l2_bih, l2_bhh,
      wcat1, wcat2, wl1b, wl2b, bcat1, bcat2, bsum1, bsum2,
      deg, cursor, pooled, N);
  graph_ranges<<<1, 128, 0, stream>>>(batch_ids, gstart, invcnt, N, G);
  embed_in2<<<cdiv_(N, 128), 256, 0, stream>>>(node_labels, node_types, node_feat, emb_label,
                                               emb_type, W_in, b_in, xb, N);

  // CSR by dst
  count_deg<<<cdiv_(ET, 256), 256, 0, stream>>>(edge_index, deg, E, N);
  int nb1 = cdiv_(N, 256);
  scan1<<<nb1, 256, 0, stream>>>(deg, offs, partials, N);
  scan2<<<1, 256, 0, stream>>>(partials, offs, nb1, N);
  scan3<<<nb1, 256, 0, stream>>>(offs, partials, N);
  fill_csr<<<cdiv_(ET, 256), 256, 0, stream>>>(edge_index, offs, cursor, csr, E, N);

  int mb = cdiv_(N, 128);
  // ---- GAT layer 1: [xl|xr] in one GEMM ----
  gemm_bf16<<<dim3(2, mb), 256, 0, stream>>>(xb, wcat1, bcat1, xlr, N, DD, 256);
  gat_agg<<<cdiv_(N, 4), 256, 0, stream>>>(xlr, 256, csr, offs, g1_att, g1_bias, xA, gsum, N);
  gn_stats2<<<cdiv_(N, 128), 256, 0, stream>>>(xA, batch_ids, gsum, gsq, N);
  gn_apply<false><<<cdiv_(N * 64, 256), 256, 0, stream>>>(
      xA, xb, nullptr, 0, batch_ids, gsum, gsq, invcnt, gn1_w, gn1_b, gn1_ms, N);
  // ---- GAT layer 2: [xl|xr|res] in one GEMM ----
  gemm_bf16<<<dim3(3, mb), 256, 0, stream>>>(xb, wcat2, bcat2, xlr, N, DD, 384);
  gat_agg<<<cdiv_(N, 4), 256, 0, stream>>>(xlr, 384, csr, offs, g2_att, g2_bias, xA, gsum, N);
  gn_stats2<<<cdiv_(N, 128), 256, 0, stream>>>(xA, batch_ids, gsum, gsq, N);
  gn_apply<true><<<cdiv_(N * 64, 256), 256, 0, stream>>>(
      xA, xb, xlr + 256, 384, batch_ids, gsum, gsq, invcnt, gn2_w, gn2_b, gn2_ms, N);
  // ---- LSTM x2: BK=64, 64-rows/wave tiles, 4 blocks/CU, XCD-swizzled ----
  int npanel = cdiv_(N, 128);
  int lblocks = 64 * cdiv_(npanel, 8);
  lstm_big<DD><<<lblocks, 256, 0, stream>>>(xb, wl1b, bsum1, h1, N);
  lstm_big<LSTMH><<<lblocks, 256, 0, stream>>>(h1, wl2b, bsum2, h2, N);
  // ---- LN + mean pool + FC ----
  ln_pool2<<<cdiv_(N, 32), 256, 0, stream>>>(h2, batch_ids, ln_w, ln_b, invcnt, pooled, N);
  fc_lsm<<<G, 64, 0, stream>>>(pooled, fc_W, fc_b, out);
}

// Round 16
// 466.380 us; speedup vs baseline: 1.1056x; 1.0076x over previous
//
#include <hip/hip_runtime.h>
#include <cstdint>
#include <cstddef>

#define DD 128
#define LSTMH 256
#define ZG 1024

typedef __attribute__((ext_vector_type(8))) short short8v;
typedef __attribute__((ext_vector_type(4))) float float4v;

static inline int cdiv_(int a, int b) { return (a + b - 1) / b; }

__device__ __forceinline__ float sigm_(float x) { return 1.f / (1.f + __expf(-x)); }
__device__ __forceinline__ float tanh_(float x) {
  float e = __expf(-2.f * fabsf(x));
  float r = (1.f - e) / (1.f + e);
  return copysignf(r, x);
}

__device__ __forceinline__ unsigned short f2bf(float f) {
  uint32_t u = __float_as_uint(f);
  u += 0x7fffu + ((u >> 16) & 1u);
  return (unsigned short)(u >> 16);
}
__device__ __forceinline__ uint32_t bfpack(float a, float b) {
  return (uint32_t)f2bf(a) | ((uint32_t)f2bf(b) << 16);
}
__device__ __forceinline__ float bflo(uint32_t u) { return __uint_as_float(u << 16); }
__device__ __forceinline__ float bfhi(uint32_t u) { return __uint_as_float(u & 0xffff0000u); }

// ------- fused prep + embed: transposes/casts/biases/zeroing + invcnt (binary search)
// + the embedding GEMV as a block-range branch (runs CONCURRENTLY with prep blocks).
// graph_ranges folded in: gstart was dead (only invcnt is consumed downstream).
__global__ __launch_bounds__(256) void prep_fused(
    const float* __restrict__ g1Wl, const float* __restrict__ g1Wr,
    const float* __restrict__ g2Wl, const float* __restrict__ g2Wr,
    const float* __restrict__ Wres, const float* __restrict__ l1Wih,
    const float* __restrict__ l2Wih, const float* __restrict__ g1bl,
    const float* __restrict__ g1br, const float* __restrict__ g2bl,
    const float* __restrict__ g2br, const float* __restrict__ bres,
    const float* __restrict__ l1bih, const float* __restrict__ l1bhh,
    const float* __restrict__ l2bih, const float* __restrict__ l2bhh,
    unsigned short* __restrict__ wcat1, unsigned short* __restrict__ wcat2,
    unsigned short* __restrict__ wl1b, unsigned short* __restrict__ wl2b,
    float* __restrict__ bcat1, float* __restrict__ bcat2,
    float* __restrict__ bsum1, float* __restrict__ bsum2,
    int* __restrict__ deg, int* __restrict__ cursor,
    float* __restrict__ pooled, const int* __restrict__ bids,
    float* __restrict__ invcnt, int Nn, int G_, int prepB,
    const int* __restrict__ labels, const int* __restrict__ types,
    const float* __restrict__ nf, const float* __restrict__ embL,
    const float* __restrict__ embT, const float* __restrict__ Wi,
    const float* __restrict__ bi, unsigned short* __restrict__ x) {
  __shared__ float f[128][34];
  if (blockIdx.x >= prepB) {
    // ---- embedding + W_in GEMV: 128 nodes/block, W in registers ----
    int base = (blockIdx.x - prepB) * 128;
    int tid = threadIdx.x;
    int ch = tid & 127, half = tid >> 7;
    float wr[33];
#pragma unroll
    for (int k = 0; k < 33; ++k) wr[k] = Wi[k * 128 + ch];
    float bb = bi[ch];
    int nmax = Nn - base < 128 ? Nn - base : 128;
    for (int e = tid; e < nmax * 32; e += 256) {
      int n = e >> 5, k = e & 31;
      f[n][k] = (k < 16) ? embL[labels[base + n] * 16 + k]
                         : embT[types[base + n] * 16 + (k - 16)];
    }
    for (int n = tid; n < nmax; n += 256) f[n][32] = nf[base + n];
    __syncthreads();
    for (int n = half; n < nmax; n += 2) {
      float acc = bb;
#pragma unroll
      for (int k = 0; k < 33; ++k) acc = fmaf(f[n][k], wr[k], acc);
      x[(size_t)(base + n) * 128 + ch] = f2bf(acc);
    }
    return;
  }
  int i = blockIdx.x * 256 + threadIdx.x;
  if (i < 81920) {  // five 128x128 transposes -> [M][K] bf16
    int seg = i >> 14, j = i & 16383;
    int m = j >> 7, k = j & 127;
    const float* src = (seg == 0) ? g1Wl : (seg == 1) ? g1Wr : (seg == 2) ? g2Wl
                       : (seg == 3) ? g2Wr : Wres;
    unsigned short* dst = (seg == 0) ? wcat1 : (seg == 1) ? wcat1 + 16384
                          : (seg == 2) ? wcat2 : (seg == 3) ? wcat2 + 16384 : wcat2 + 32768;
    dst[j] = f2bf(src[k * 128 + m]);
    return;
  }
  i -= 81920;
  if (i < 131072) { wl1b[i] = f2bf(l1Wih[i]); return; }
  i -= 131072;
  if (i < 262144) { wl2b[i] = f2bf(l2Wih[i]); return; }
  i -= 262144;
  if (i < 256) { bcat1[i] = (i < 128) ? g1bl[i] : g1br[i - 128]; return; }
  i -= 256;
  if (i < 384) {
    bcat2[i] = (i < 128) ? g2bl[i] : (i < 256 ? g2br[i - 128] : bres[i - 256]);
    return;
  }
  i -= 384;
  if (i < 1024) { bsum1[i] = l1bih[i] + l1bhh[i]; return; }
  i -= 1024;
  if (i < 1024) { bsum2[i] = l2bih[i] + l2bhh[i]; return; }
  i -= 1024;
  if (i < Nn) { deg[i] = 0; return; }
  i -= Nn;
  if (i < Nn) { cursor[i] = 0; return; }
  i -= Nn;
  if (i < 16384) { pooled[i] = 0.f; return; }
  i -= 16384;
  if (i < G_) {  // invcnt[i] via two lower_bound searches on sorted bids
    int lo = 0, hi = Nn;
    while (lo < hi) { int mid = (lo + hi) >> 1; if (bids[mid] < i) lo = mid + 1; else hi = mid; }
    int lo2 = lo, hi2 = Nn, tt = i + 1;
    while (lo2 < hi2) { int mid = (lo2 + hi2) >> 1; if (bids[mid] < tt) lo2 = mid + 1; else hi2 = mid; }
    int c = lo2 - lo;
    invcnt[i] = (c > 0) ? 1.f / (float)c : 0.f;
    return;
  }
}

// ---------------- CSR build ----------------
__global__ void count_deg(const int* __restrict__ ei, int* __restrict__ deg, int E_, int N_) {
  int i = blockIdx.x * 256 + threadIdx.x;
  if (i < E_) atomicAdd(&deg[ei[E_ + i]], 1);
  else if (i < E_ + N_) atomicAdd(&deg[i - E_], 1);
}

__global__ __launch_bounds__(256) void scan1(const int* __restrict__ deg, int* __restrict__ offs,
                                             int* __restrict__ partials, int N_) {
  __shared__ int buf[2][256];
  int tid = threadIdx.x;
  int i = blockIdx.x * 256 + tid;
  int v = (i < N_) ? deg[i] : 0;
  buf[0][tid] = v;
  __syncthreads();
  int cur = 0;
#pragma unroll
  for (int d = 1; d < 256; d <<= 1) {
    int xv = buf[cur][tid];
    if (tid >= d) xv += buf[cur][tid - d];
    buf[cur ^ 1][tid] = xv;
    cur ^= 1;
    __syncthreads();
  }
  int incl = buf[cur][tid];
  if (i < N_) offs[i] = incl - v;
  if (tid == 255) partials[blockIdx.x] = incl;
}

__global__ __launch_bounds__(256) void scan2(int* __restrict__ partials, int* __restrict__ offs,
                                             int nb, int N_) {
  __shared__ int buf[2][256];
  int tid = threadIdx.x;
  int v = (tid < nb) ? partials[tid] : 0;
  buf[0][tid] = v;
  __syncthreads();
  int cur = 0;
#pragma unroll
  for (int d = 1; d < 256; d <<= 1) {
    int xv = buf[cur][tid];
    if (tid >= d) xv += buf[cur][tid - d];
    buf[cur ^ 1][tid] = xv;
    cur ^= 1;
    __syncthreads();
  }
  int incl = buf[cur][tid];
  if (tid < nb) partials[tid] = incl - v;
  if (tid == 255) offs[N_] = incl;
}

__global__ void scan3(int* __restrict__ offs, const int* __restrict__ partials, int N_) {
  int i = blockIdx.x * 256 + threadIdx.x;
  if (i < N_) offs[i] += partials[blockIdx.x];
}

__global__ void fill_csr(const int* __restrict__ ei, const int* __restrict__ offs,
                         int* __restrict__ cursor, int* __restrict__ csr, int E_, int N_) {
  int i = blockIdx.x * 256 + threadIdx.x;
  int s, d;
  if (i < E_) { s = ei[i]; d = ei[E_ + i]; }
  else if (i < E_ + N_) { s = d = i - E_; }
  else return;
  int pos = offs[d] + atomicAdd(&cursor[d], 1);
  csr[pos] = s;
}

// ---------------- bf16 MFMA GEMM: C[M,Ncols] bf16 = A[M,K]bf16 @ B'[Ncols,K]^T + bias
__global__ __launch_bounds__(256) void gemm_bf16(
    const unsigned short* __restrict__ A, const unsigned short* __restrict__ Bp,
    const float* __restrict__ bias, unsigned short* __restrict__ C, int M, int K, int Ncols) {
  __shared__ unsigned short As[128 * 40];
  __shared__ unsigned short Bs[128 * 40];
  int tid = threadIdx.x;
  int lane = tid & 63;
  int wid = tid >> 6;
  int rowBase = blockIdx.y * 128, colBase = blockIdx.x * 128;
  int wr = (wid >> 1) * 64, wc = (wid & 1) * 64;
  int fr = lane & 15, fg = lane >> 4;
  float4v acc[4][4];
#pragma unroll
  for (int i = 0; i < 4; ++i)
#pragma unroll
    for (int j = 0; j < 4; ++j) acc[i][j] = (float4v){0.f, 0.f, 0.f, 0.f};

  int sr = tid >> 2;
  int sc = tid & 3;
  int off_lo = (sc < 2) ? 32 * sc : 32 * sc - 56;

  for (int k0 = 0; k0 < K; k0 += 32) {
#pragma unroll
    for (int it = 0; it < 2; ++it) {
      int r = it * 64 + sr;
      uint4 va = make_uint4(0u, 0u, 0u, 0u);
      if (rowBase + r < M)
        va = *(const uint4*)(A + (size_t)(rowBase + r) * K + k0 + sc * 8);
      char* arow = (char*)(As + r * 40);
      *(uint2*)(arow + off_lo) = make_uint2(va.x, va.y);
      *(uint2*)(arow + off_lo + 16) = make_uint2(va.z, va.w);
      uint4 vb = *(const uint4*)(Bp + (size_t)(colBase + r) * K + k0 + sc * 8);
      char* brow = (char*)(Bs + r * 40);
      *(uint2*)(brow + off_lo) = make_uint2(vb.x, vb.y);
      *(uint2*)(brow + off_lo + 16) = make_uint2(vb.z, vb.w);
    }
    __syncthreads();
    short8v af[4], bfv[4];
#pragma unroll
    for (int i = 0; i < 4; ++i)
      af[i] = *(const short8v*)((const char*)As + (wr + 16 * i + fr) * 80 + fg * 16);
#pragma unroll
    for (int j = 0; j < 4; ++j)
      bfv[j] = *(const short8v*)((const char*)Bs + (wc + 16 * j + fr) * 80 + fg * 16);
#pragma unroll
    for (int i = 0; i < 4; ++i)
#pragma unroll
      for (int j = 0; j < 4; ++j)
        acc[i][j] = __builtin_amdgcn_mfma_f32_16x16x32_bf16(af[i], bfv[j], acc[i][j], 0, 0, 0);
    __syncthreads();
  }
#pragma unroll
  for (int j = 0; j < 4; ++j) {
    int gc = colBase + wc + 16 * j + fr;
    float bv = bias[gc];
#pragma unroll
    for (int i = 0; i < 4; ++i) {
      int gr0 = rowBase + wr + 16 * i + fg * 4;
#pragma unroll
      for (int rg = 0; rg < 4; ++rg) {
        int gr = gr0 + rg;
        if (gr < M) C[(size_t)gr * Ncols + gc] = f2bf(acc[i][j][rg] + bv);
      }
    }
  }
}

// ---------------- GATv2 aggregation: 1 wave/node, 4 edges in flight, per-head softmax ----
// 16 lanes/edge, 8 ch/lane; a head (32 ch) spans 4 aligned lanes -> reduce is xor 1,2 ONLY.
// Merge the 4 edge-slot states via xor 16,32. (8-edge variant regressed: deg~17 makes the
// 4-stage/16-ch merge dominate — measured r10.)
// Also zeroes gsum+gsq (64KB) in the first 16 blocks (safe: prior layer's gn_apply done).
__global__ __launch_bounds__(256) void gat_agg(
    const unsigned short* __restrict__ xlr, int stride,
    const int* __restrict__ csr, const int* __restrict__ offs,
    const float* __restrict__ att, const float* __restrict__ bias,
    unsigned short* __restrict__ out, float* __restrict__ gz, int N) {
  int zt = blockIdx.x * 256 + threadIdx.x;
  if (zt < 4096) *(float4*)(gz + zt * 4) = make_float4(0.f, 0.f, 0.f, 0.f);
  int wid = zt >> 6;
  if (wid >= N) return;
  int lane = threadIdx.x & 63;
  int q = lane >> 4, ql = lane & 15;   // edge slot, channel group (8 ch each)
  float4 aA = *(const float4*)&att[ql * 8];
  float4 aB = *(const float4*)&att[ql * 8 + 4];
  uint4 ur = *(const uint4*)(xlr + (size_t)wid * stride + 128 + ql * 8);
  float r0 = bflo(ur.x), r1 = bfhi(ur.x), r2 = bflo(ur.y), r3 = bfhi(ur.y);
  float r4 = bflo(ur.z), r5 = bfhi(ur.z), r6 = bflo(ur.w), r7 = bfhi(ur.w);
  float m = -1e30f, L = 0.f;
  float s0 = 0.f, s1 = 0.f, s2 = 0.f, s3 = 0.f, s4 = 0.f, s5 = 0.f, s6 = 0.f, s7 = 0.f;
  int js = offs[wid], je = offs[wid + 1];
  for (int j = js + q; j < je; j += 4) {
    int s = csr[j];
    uint4 u = *(const uint4*)(xlr + (size_t)s * stride + ql * 8);
    float x0 = bflo(u.x), x1 = bfhi(u.x), x2 = bflo(u.y), x3 = bfhi(u.y);
    float x4 = bflo(u.z), x5 = bfhi(u.z), x6 = bflo(u.w), x7 = bfhi(u.w);
    float v0 = fmaxf(r0 + x0, 0.2f * (r0 + x0));
    float v1 = fmaxf(r1 + x1, 0.2f * (r1 + x1));
    float v2 = fmaxf(r2 + x2, 0.2f * (r2 + x2));
    float v3 = fmaxf(r3 + x3, 0.2f * (r3 + x3));
    float v4 = fmaxf(r4 + x4, 0.2f * (r4 + x4));
    float v5 = fmaxf(r5 + x5, 0.2f * (r5 + x5));
    float v6 = fmaxf(r6 + x6, 0.2f * (r6 + x6));
    float v7 = fmaxf(r7 + x7, 0.2f * (r7 + x7));
    float p = aA.x * v0 + aA.y * v1 + aA.z * v2 + aA.w * v3 +
              aB.x * v4 + aB.y * v5 + aB.z * v6 + aB.w * v7;
    p += __shfl_xor(p, 1); p += __shfl_xor(p, 2);   // per-head reduce (4 lanes = 32 ch)
    float mn = fmaxf(m, p);
    float ea = __expf(p - mn);
    float es = __expf(m - mn);
    L = L * es + ea;
    s0 = s0 * es + ea * x0; s1 = s1 * es + ea * x1;
    s2 = s2 * es + ea * x2; s3 = s3 * es + ea * x3;
    s4 = s4 * es + ea * x4; s5 = s5 * es + ea * x5;
    s6 = s6 * es + ea * x6; s7 = s7 * es + ea * x7;
    m = mn;
  }
  // merge the 4 edge-slot states (per head/channel-slice)
#pragma unroll
  for (int d = 16; d <= 32; d <<= 1) {
    float mo = __shfl_xor(m, d), Lo = __shfl_xor(L, d);
    float t0 = __shfl_xor(s0, d), t1 = __shfl_xor(s1, d);
    float t2 = __shfl_xor(s2, d), t3 = __shfl_xor(s3, d);
    float t4 = __shfl_xor(s4, d), t5 = __shfl_xor(s5, d);
    float t6 = __shfl_xor(s6, d), t7 = __shfl_xor(s7, d);
    float mn = fmaxf(m, mo);
    float e0 = __expf(m - mn), e1 = __expf(mo - mn);
    L = L * e0 + Lo * e1;
    s0 = s0 * e0 + t0 * e1; s1 = s1 * e0 + t1 * e1;
    s2 = s2 * e0 + t2 * e1; s3 = s3 * e0 + t3 * e1;
    s4 = s4 * e0 + t4 * e1; s5 = s5 * e0 + t5 * e1;
    s6 = s6 * e0 + t6 * e1; s7 = s7 * e0 + t7 * e1;
    m = mn;
  }
  if (q == 0) {
    float inv = 1.f / L;
    float4 bA = *(const float4*)&bias[ql * 8];
    float4 bB = *(const float4*)&bias[ql * 8 + 4];
    uint4 ov;
    ov.x = bfpack(s0 * inv + bA.x, s1 * inv + bA.y);
    ov.y = bfpack(s2 * inv + bA.z, s3 * inv + bA.w);
    ov.z = bfpack(s4 * inv + bB.x, s5 * inv + bB.y);
    ov.w = bfpack(s6 * inv + bB.z, s7 * inv + bB.w);
    *(uint4*)(out + (size_t)wid * DD + ql * 8) = ov;
  }
}

// ---------------- GraphNorm stats (bf16 input, uint-vectorized) ----------------
__global__ __launch_bounds__(256) void gn_stats2(const unsigned short* __restrict__ x,
                                                 const int* __restrict__ bids,
                                                 float* __restrict__ gsum,
                                                 float* __restrict__ gsq, int N) {
  int base = blockIdx.x * 128;
  int cp = threadIdx.x & 63;   // channel pair
  int sub = threadIdx.x >> 6;  // row offset 0..3
  int end = base + 128 < N ? base + 128 : N;
  int curg = -1;
  float s0 = 0.f, s1 = 0.f, q0 = 0.f, q1 = 0.f;
  for (int r = base + sub; r < end; r += 4) {
    int g = bids[r];
    if (g != curg) {
      if (curg >= 0) {
        atomicAdd(&gsum[curg * DD + cp * 2], s0);
        atomicAdd(&gsum[curg * DD + cp * 2 + 1], s1);
        atomicAdd(&gsq[curg * DD + cp * 2], q0);
        atomicAdd(&gsq[curg * DD + cp * 2 + 1], q1);
      }
      curg = g; s0 = s1 = q0 = q1 = 0.f;
    }
    uint32_t u = *(const uint32_t*)(x + (size_t)r * DD + cp * 2);
    float v0 = bflo(u), v1 = bfhi(u);
    s0 += v0; q0 += v0 * v0; s1 += v1; q1 += v1 * v1;
  }
  if (curg >= 0) {
    atomicAdd(&gsum[curg * DD + cp * 2], s0);
    atomicAdd(&gsum[curg * DD + cp * 2 + 1], s1);
    atomicAdd(&gsq[curg * DD + cp * 2], q0);
    atomicAdd(&gsq[curg * DD + cp * 2 + 1], q1);
  }
}

// ---------------- GraphNorm apply + ELU (+residual) : bf16 in -> bf16 out --------------
template <bool ADDRES>
__global__ void gn_apply(const unsigned short* __restrict__ xin,
                         unsigned short* __restrict__ xout,
                         const unsigned short* __restrict__ res, int resStride,
                         const int* __restrict__ bids, const float* __restrict__ gsum,
                         const float* __restrict__ gsq, const float* __restrict__ invcnt,
                         const float* __restrict__ w, const float* __restrict__ b,
                         const float* __restrict__ ms, int N) {
  int idx = blockIdx.x * 256 + threadIdx.x;
  if (idx >= N * 64) return;
  int n = idx >> 6, cp = idx & 63;
  int g = bids[n];
  float ic = invcnt[g];
  float2 sm = *(const float2*)&gsum[g * DD + cp * 2];
  float2 sq = *(const float2*)&gsq[g * DD + cp * 2];
  float2 w2 = *(const float2*)&w[cp * 2];
  float2 b2 = *(const float2*)&b[cp * 2];
  float2 m2 = *(const float2*)&ms[cp * 2];
  uint32_t u = *(const uint32_t*)(xin + (size_t)n * DD + cp * 2);
  float mean0 = sm.x * ic, mean1 = sm.y * ic;
  float mm0 = mean0 * m2.x, mm1 = mean1 * m2.y;
  float var0 = sq.x * ic - mm0 * (2.f * mean0 - mm0);
  float var1 = sq.y * ic - mm1 * (2.f * mean1 - mm1);
  float v0 = (bflo(u) - mm0) * rsqrtf(var0 + 1e-5f) * w2.x + b2.x;
  float v1 = (bfhi(u) - mm1) * rsqrtf(var1 + 1e-5f) * w2.y + b2.y;
  if (ADDRES) {
    uint32_t ur = *(const uint32_t*)(res + (size_t)n * resStride + cp * 2);
    v0 += bflo(ur); v1 += bfhi(ur);
  }
  v0 = v0 > 0.f ? v0 : (__expf(v0) - 1.f);
  v1 = v1 > 0.f ? v1 : (__expf(v1) - 1.f);
  *(uint32_t*)(xout + (size_t)n * DD + cp * 2) = bfpack(v0, v1);
}

// ---------------- LSTM step: BK=64, 256 thr (4 waves, 64 rows/wave), reg-prefetch --------
// Block: 128 rows x 32 h-channels (96 gate rows i|g|o), 30.7KB LDS, 4 blocks/CU.
// Best measured config (r12: 62us, FETCH 14MB, WRITE 25MB, no spill). Do NOT perturb:
// (256,5) spilled (r11: WRITE 141MB); L2-direct MFMA latency-bound (r13: 106us);
// linear-k single-store layout spilled (r14: WRITE 84MB).
template <int KD>
__global__ __launch_bounds__(256, 4) void lstm_big(
    const unsigned short* __restrict__ A, const unsigned short* __restrict__ Bp,
    const float* __restrict__ bsum, unsigned short* __restrict__ H, int M) {
  __shared__ __attribute__((aligned(16))) char As_[128 * 136];
  __shared__ __attribute__((aligned(16))) char Ws_[96 * 136];
  const int NPH = KD / 64;
  int npanel = (M + 127) >> 7;
  int b = blockIdx.x;
  int g8 = b & 7, inner = b >> 3;
  int p = g8 + 8 * (inner >> 3);
  int cc = inner & 7;
  if (p >= npanel) return;
  int rowBase = p << 7;
  int ch0 = cc * 32;

  int tid = threadIdx.x;
  int lane = tid & 63;
  int wid = tid >> 6;
  int wr2 = wid >> 1;   // 0..1 row-group (64 rows)
  int wc2 = wid & 1;    // 0..1 col-group (16 ch -> 48 gate rows)
  int fr = lane & 15, fg = lane >> 4;

  // A staging: 4 16B units/thread (1024 units = 128 rows x 8)
  int aldst[4], agoff[4];
  bool aval[4];
#pragma unroll
  for (int q = 0; q < 4; ++q) {
    int e = q * 256 + tid;
    int r = e >> 3, kk = e & 7;
    int c = kk >> 2, sc = kk & 3;
    int olo = (sc < 2) ? 32 * sc : 32 * sc - 56;
    aldst[q] = r * 136 + c * 64 + olo;
    aval[q] = (rowBase + r) < M;
    agoff[q] = (rowBase + r) * KD + c * 32 + sc * 8;
  }
  // W staging: 3 units/thread (768 units = 96 rows x 8)
  int wldst[3], wgoff[3];
#pragma unroll
  for (int q = 0; q < 3; ++q) {
    int e = q * 256 + tid;
    int wrow = e >> 3, kk = e & 7;
    int c = kk >> 2, sc = kk & 3;
    int half = wrow >= 48 ? 1 : 0;
    int r3 = wrow - 48 * half;
    int grp = r3 >> 4;
    int goff = (grp == 0) ? 0 : (grp == 1 ? 512 : 768);
    int grow = goff + ch0 + 16 * half + (r3 & 15);
    int olo = (sc < 2) ? 32 * sc : 32 * sc - 56;
    wldst[q] = wrow * 136 + c * 64 + olo;
    wgoff[q] = grow * KD + c * 32 + sc * 8;
  }

  float4v acc[4][3];
#pragma unroll
  for (int i = 0; i < 4; ++i)
#pragma unroll
    for (int j = 0; j < 3; ++j) acc[i][j] = (float4v){0.f, 0.f, 0.f, 0.f};

  uint4 va[4], vw[3];
#pragma unroll
  for (int q = 0; q < 4; ++q) {
    va[q] = make_uint4(0u, 0u, 0u, 0u);
    if (aval[q]) va[q] = *(const uint4*)(A + agoff[q]);
  }
#pragma unroll
  for (int q = 0; q < 3; ++q) vw[q] = *(const uint4*)(Bp + wgoff[q]);

#pragma unroll
  for (int ph = 0; ph < NPH; ++ph) {
    if (ph) __syncthreads();
#pragma unroll
    for (int q = 0; q < 4; ++q) {
      char* dst = As_ + aldst[q];
      *(uint2*)(dst) = make_uint2(va[q].x, va[q].y);
      *(uint2*)(dst + 16) = make_uint2(va[q].z, va[q].w);
    }
#pragma unroll
    for (int q = 0; q < 3; ++q) {
      char* dst = Ws_ + wldst[q];
      *(uint2*)(dst) = make_uint2(vw[q].x, vw[q].y);
      *(uint2*)(dst + 16) = make_uint2(vw[q].z, vw[q].w);
    }
    __syncthreads();
    if (ph + 1 < NPH) {
      int koff = (ph + 1) * 64;
#pragma unroll
      for (int q = 0; q < 4; ++q) {
        va[q] = make_uint4(0u, 0u, 0u, 0u);
        if (aval[q]) va[q] = *(const uint4*)(A + agoff[q] + koff);
      }
#pragma unroll
      for (int q = 0; q < 3; ++q) vw[q] = *(const uint4*)(Bp + wgoff[q] + koff);
    }
    __builtin_amdgcn_s_setprio(1);
#pragma unroll
    for (int c = 0; c < 2; ++c) {
      short8v af[4], bf[3];
#pragma unroll
      for (int i = 0; i < 4; ++i)
        af[i] = *(const short8v*)(As_ + (64 * wr2 + 16 * i + fr) * 136 + c * 64 + fg * 16);
#pragma unroll
      for (int j = 0; j < 3; ++j)
        bf[j] = *(const short8v*)(Ws_ + (48 * wc2 + 16 * j + fr) * 136 + c * 64 + fg * 16);
#pragma unroll
      for (int i = 0; i < 4; ++i)
#pragma unroll
        for (int j = 0; j < 3; ++j)
          acc[i][j] = __builtin_amdgcn_mfma_f32_16x16x32_bf16(af[i], bf[j], acc[i][j], 0, 0, 0);
    }
    __builtin_amdgcn_s_setprio(0);
  }
  // epilogue: lane owns channel ch for 16 rows; activations in registers
  int chL = 16 * wc2 + fr;
  int ch = ch0 + chL;
  float bi = bsum[ch], bg = bsum[512 + ch], bo = bsum[768 + ch];
  unsigned short hv[16];
#pragma unroll
  for (int i = 0; i < 4; ++i) {
#pragma unroll
    for (int rg = 0; rg < 4; ++rg) {
      float iv = acc[i][0][rg] + bi;
      float gv = acc[i][1][rg] + bg;
      float ov = acc[i][2][rg] + bo;
      float c = sigm_(iv) * tanh_(gv);
      hv[i * 4 + rg] = f2bf(sigm_(ov) * tanh_(c));
    }
  }
  __syncthreads();
  unsigned short* Hs = (unsigned short*)As_;  // [128][40] = 10240B
#pragma unroll
  for (int i = 0; i < 4; ++i) {
#pragma unroll
    for (int rg = 0; rg < 4; ++rg) {
      int row = 64 * wr2 + 16 * i + 4 * fg + rg;
      Hs[row * 40 + chL] = hv[i * 4 + rg];
    }
  }
  __syncthreads();
#pragma unroll
  for (int q = 0; q < 2; ++q) {
    int e = q * 256 + tid;
    int row = e >> 2, seg = e & 3;
    if (rowBase + row < M) {
      uint4 v = *(const uint4*)(Hs + row * 40 + seg * 8);
      *(uint4*)(H + (size_t)(rowBase + row) * LSTMH + ch0 + seg * 8) = v;
    }
  }
}

// ---------------- LayerNorm + mean pool: 1 wave per 8 rows, register pooling ----------
__global__ __launch_bounds__(256) void ln_pool2(
    const unsigned short* __restrict__ h2, const int* __restrict__ bids,
    const float* __restrict__ lnw, const float* __restrict__ lnb,
    const float* __restrict__ invcnt, float* __restrict__ pooled, int N) {
  int wave = (blockIdx.x * 256 + threadIdx.x) >> 6;
  int lane = threadIdx.x & 63;
  int r0 = wave * 8;
  if (r0 >= N) return;
  float4 w4 = *(const float4*)&lnw[lane * 4];
  float4 b4 = *(const float4*)&lnb[lane * 4];
  float p0 = 0.f, p1 = 0.f, p2 = 0.f, p3 = 0.f;
  int curg = bids[r0];
  int rend = r0 + 8 < N ? r0 + 8 : N;
  for (int r = r0; r < rend; ++r) {
    int g = bids[r];
    if (g != curg) {
      float ic = invcnt[curg];
      atomicAdd(&pooled[curg * LSTMH + lane * 4 + 0], p0 * ic);
      atomicAdd(&pooled[curg * LSTMH + lane * 4 + 1], p1 * ic);
      atomicAdd(&pooled[curg * LSTMH + lane * 4 + 2], p2 * ic);
      atomicAdd(&pooled[curg * LSTMH + lane * 4 + 3], p3 * ic);
      p0 = p1 = p2 = p3 = 0.f;
      curg = g;
    }
    uint2 u = *(const uint2*)(h2 + (size_t)r * LSTMH + lane * 4);
    float v0 = bflo(u.x), v1 = bfhi(u.x), v2 = bflo(u.y), v3 = bfhi(u.y);
    float s = v0 + v1 + v2 + v3;
    float q = v0 * v0 + v1 * v1 + v2 * v2 + v3 * v3;
#pragma unroll
    for (int d = 1; d < 64; d <<= 1) { s += __shfl_xor(s, d); q += __shfl_xor(q, d); }
    float mu = s * (1.f / 256.f);
    float var = q * (1.f / 256.f) - mu * mu;
    float rs = rsqrtf(var + 1e-5f);
    p0 += w4.x * (v0 - mu) * rs + b4.x;
    p1 += w4.y * (v1 - mu) * rs + b4.y;
    p2 += w4.z * (v2 - mu) * rs + b4.z;
    p3 += w4.w * (v3 - mu) * rs + b4.w;
  }
  float ic = invcnt[curg];
  atomicAdd(&pooled[curg * LSTMH + lane * 4 + 0], p0 * ic);
  atomicAdd(&pooled[curg * LSTMH + lane * 4 + 1], p1 * ic);
  atomicAdd(&pooled[curg * LSTMH + lane * 4 + 2], p2 * ic);
  atomicAdd(&pooled[curg * LSTMH + lane * 4 + 3], p3 * ic);
}

// ---------------- FC + log_softmax ----------------
__global__ __launch_bounds__(64) void fc_lsm(const float* __restrict__ pooled,
                                             const float* __restrict__ W,
                                             const float* __restrict__ b, float* __restrict__ out) {
  int g = blockIdx.x;
  int t = threadIdx.x;
  float l0 = 0.f, l1 = 0.f, l2 = 0.f, l3 = 0.f;
  for (int k = t; k < LSTMH; k += 64) {
    float p = pooled[g * LSTMH + k];
    l0 += p * W[k * 4 + 0];
    l1 += p * W[k * 4 + 1];
    l2 += p * W[k * 4 + 2];
    l3 += p * W[k * 4 + 3];
  }
#pragma unroll
  for (int d = 1; d < 64; d <<= 1) {
    l0 += __shfl_xor(l0, d); l1 += __shfl_xor(l1, d);
    l2 += __shfl_xor(l2, d); l3 += __shfl_xor(l3, d);
  }
  if (t == 0) {
    float z[4] = {l0 + b[0], l1 + b[1], l2 + b[2], l3 + b[3]};
    float mx = fmaxf(fmaxf(z[0], z[1]), fmaxf(z[2], z[3]));
    float sum = __expf(z[0] - mx) + __expf(z[1] - mx) + __expf(z[2] - mx) + __expf(z[3] - mx);
    float ls = logf(sum);
#pragma unroll
    for (int o = 0; o < 4; ++o) out[g * 4 + o] = z[o] - mx - ls;
  }
}

// ---------------- host launch ----------------
extern "C" void kernel_launch(void* const* d_in, const int* in_sizes, int n_in,
                              void* d_out, int out_size, void* d_ws, size_t ws_size,
                              hipStream_t stream) {
  const int* node_labels = (const int*)d_in[0];
  const int* node_types = (const int*)d_in[1];
  const float* node_feat = (const float*)d_in[2];
  const int* edge_index = (const int*)d_in[3];
  const int* batch_ids = (const int*)d_in[4];
  const float* emb_label = (const float*)d_in[5];
  const float* emb_type = (const float*)d_in[6];
  const float* W_in = (const float*)d_in[7];
  const float* b_in = (const float*)d_in[8];
  const float* g1_Wl = (const float*)d_in[9];
  const float* g1_bl = (const float*)d_in[10];
  const float* g1_Wr = (const float*)d_in[11];
  const float* g1_br = (const float*)d_in[12];
  const float* g1_att = (const float*)d_in[13];
  const float* g1_bias = (const float*)d_in[14];
  const float* gn1_w = (const float*)d_in[15];
  const float* gn1_b = (const float*)d_in[16];
  const float* gn1_ms = (const float*)d_in[17];
  const float* g2_Wl = (const float*)d_in[18];
  const float* g2_bl = (const float*)d_in[19];
  const float* g2_Wr = (const float*)d_in[20];
  const float* g2_br = (const float*)d_in[21];
  const float* g2_att = (const float*)d_in[22];
  const float* g2_bias = (const float*)d_in[23];
  const float* gn2_w = (const float*)d_in[24];
  const float* gn2_b = (const float*)d_in[25];
  const float* gn2_ms = (const float*)d_in[26];
  const float* W_res = (const float*)d_in[27];
  const float* b_res = (const float*)d_in[28];
  const float* l1_Wih = (const float*)d_in[29];
  const float* l1_bih = (const float*)d_in[31];
  const float* l1_bhh = (const float*)d_in[32];
  const float* l2_Wih = (const float*)d_in[33];
  const float* l2_bih = (const float*)d_in[35];
  const float* l2_bhh = (const float*)d_in[36];
  const float* ln_w = (const float*)d_in[37];
  const float* ln_b = (const float*)d_in[38];
  const float* fc_W = (const float*)d_in[39];
  const float* fc_b = (const float*)d_in[40];
  float* out = (float*)d_out;

  const int N = in_sizes[0];
  const int E = in_sizes[3] / 2;
  const int G = out_size / 4;
  const int ET = E + N;

  char* wsb = (char*)d_ws;
  size_t off = 0;
  auto alloc = [&](size_t bytes) -> void* {
    void* p = (void*)(wsb + off);
    off = (off + bytes + 255) & ~(size_t)255;
    return p;
  };
  unsigned short* xA = (unsigned short*)alloc((size_t)N * 512);       // gat out bf16; later h2
  unsigned short* xb = (unsigned short*)alloc((size_t)N * DD * 2);    // bf16 x / x1 / x2
  unsigned short* xlr = (unsigned short*)alloc((size_t)N * 384 * 2);  // xl|xr(|res); later h1
  int* deg = (int*)alloc((size_t)N * 4);
  int* offs = (int*)alloc((size_t)(N + 1) * 4);
  int* cursor = (int*)alloc((size_t)N * 4);
  int* partials = (int*)alloc(1024);
  int* csr = (int*)alloc((size_t)ET * 4);
  float* invcnt = (float*)alloc((size_t)G * 4);
  float* gsum = (float*)alloc((size_t)G * DD * 4);   // contiguous with gsq (32KB each)
  float* gsq = (float*)alloc((size_t)G * DD * 4);
  float* pooled = (float*)alloc((size_t)G * LSTMH * 4);
  float* bcat1 = (float*)alloc(256 * 4);
  float* bcat2 = (float*)alloc(384 * 4);
  float* bsum1 = (float*)alloc(ZG * 4);
  float* bsum2 = (float*)alloc(ZG * 4);
  unsigned short* wcat1 = (unsigned short*)alloc((size_t)256 * DD * 2);
  unsigned short* wcat2 = (unsigned short*)alloc((size_t)384 * DD * 2);
  unsigned short* wl1b = (unsigned short*)alloc((size_t)ZG * DD * 2);
  unsigned short* wl2b = (unsigned short*)alloc((size_t)ZG * LSTMH * 2);
  (void)ws_size; (void)n_in;

  unsigned short* h1 = xlr;   // [N][256] bf16, written after xlr dead
  unsigned short* h2 = xA;    // [N][256] bf16, written after xA dead

  int prepItems = 477824 + 2 * N + 16384 + G;
  int prepB = cdiv_(prepItems, 256);
  int embB = cdiv_(N, 128);
  prep_fused<<<prepB + embB, 256, 0, stream>>>(
      g1_Wl, g1_Wr, g2_Wl, g2_Wr, W_res, l1_Wih, l2_Wih,
      g1_bl, g1_br, g2_bl, g2_br, b_res, l1_bih, l1_bhh, l2_bih, l2_bhh,
      wcat1, wcat2, wl1b, wl2b, bcat1, bcat2, bsum1, bsum2,
      deg, cursor, pooled, batch_ids, invcnt, N, G, prepB,
      node_labels, node_types, node_feat, emb_label, emb_type, W_in, b_in, xb);

  // CSR by dst
  count_deg<<<cdiv_(ET, 256), 256, 0, stream>>>(edge_index, deg, E, N);
  int nb1 = cdiv_(N, 256);
  scan1<<<nb1, 256, 0, stream>>>(deg, offs, partials, N);
  scan2<<<1, 256, 0, stream>>>(partials, offs, nb1, N);
  scan3<<<nb1, 256, 0, stream>>>(offs, partials, N);
  fill_csr<<<cdiv_(ET, 256), 256, 0, stream>>>(edge_index, offs, cursor, csr, E, N);

  int mb = cdiv_(N, 128);
  // ---- GAT layer 1: [xl|xr] in one GEMM ----
  gemm_bf16<<<dim3(2, mb), 256, 0, stream>>>(xb, wcat1, bcat1, xlr, N, DD, 256);
  gat_agg<<<cdiv_(N, 4), 256, 0, stream>>>(xlr, 256, csr, offs, g1_att, g1_bias, xA, gsum, N);
  gn_stats2<<<cdiv_(N, 128), 256, 0, stream>>>(xA, batch_ids, gsum, gsq, N);
  gn_apply<false><<<cdiv_(N * 64, 256), 256, 0, stream>>>(
      xA, xb, nullptr, 0, batch_ids, gsum, gsq, invcnt, gn1_w, gn1_b, gn1_ms, N);
  // ---- GAT layer 2: [xl|xr|res] in one GEMM ----
  gemm_bf16<<<dim3(3, mb), 256, 0, stream>>>(xb, wcat2, bcat2, xlr, N, DD, 384);
  gat_agg<<<cdiv_(N, 4), 256, 0, stream>>>(xlr, 384, csr, offs, g2_att, g2_bias, xA, gsum, N);
  gn_stats2<<<cdiv_(N, 128), 256, 0, stream>>>(xA, batch_ids, gsum, gsq, N);
  gn_apply<true><<<cdiv_(N * 64, 256), 256, 0, stream>>>(
      xA, xb, xlr + 256, 384, batch_ids, gsum, gsq, invcnt, gn2_w, gn2_b, gn2_ms, N);
  // ---- LSTM x2: BK=64, 64-rows/wave tiles, 4 blocks/CU, XCD-swizzled ----
  int npanel = cdiv_(N, 128);
  int lblocks = 64 * cdiv_(npanel, 8);
  lstm_big<DD><<<lblocks, 256, 0, stream>>>(xb, wl1b, bsum1, h1, N);
  lstm_big<LSTMH><<<lblocks, 256, 0, stream>>>(h1, wl2b, bsum2, h2, N);
  // ---- LN + mean pool + FC ----
  ln_pool2<<<cdiv_(N, 32), 256, 0, stream>>>(h2, batch_ids, ln_w, ln_b, invcnt, pooled, N);
  fc_lsm<<<G, 64, 0, stream>>>(pooled, fc_W, fc_b, out);
}